// Round 6
// baseline (425.933 us; speedup 1.0000x reference)
//
#include <hip/hip_runtime.h>
#include <hip/hip_bf16.h>
#include <math.h>

#define LSEQ 16384
#define DIN  192
#define GCH  512
#define TCH  32

typedef float f4v __attribute__((ext_vector_type(4)));
typedef short s8v __attribute__((ext_vector_type(8)));
typedef unsigned short u16x8 __attribute__((ext_vector_type(8)));

__device__ __forceinline__ float siluf(float x) { return x / (1.0f + __expf(-x)); }
__device__ __forceinline__ unsigned short f2bf(float f) {
  unsigned int u = __float_as_uint(f);
  unsigned int r = (u + 0x7FFFu + ((u >> 16) & 1u)) >> 16;
  return (unsigned short)r;
}
__device__ __forceinline__ float bf2f(unsigned short s) {
  return __uint_as_float(((unsigned int)s) << 16);
}

// ---------------- weight pre-pack to bf16 ----------------
__global__ __launch_bounds__(256) void k_packw(const float* __restrict__ c1w,
    const float* __restrict__ c2w, const float* __restrict__ c3w,
    const float* __restrict__ Win, const float* __restrict__ Wx,
    const float* __restrict__ Wout, unsigned short* __restrict__ P) {
  int i = blockIdx.x * 256 + threadIdx.x;
  if (i >= 184320) return;
  if (i < 27648) { P[i] = f2bf(c1w[i]); return; }
  int j = i - 27648;
  if (j < 82944) {
    int cc = j / 27648, r = j - cc * 27648;
    int kk = r / 3072, r2 = r - kk * 3072;
    int oc = r2 >> 5, icl = r2 & 31;
    int ky = kk / 3, kx = kk - ky * 3;
    P[i] = f2bf(c2w[((oc * 96 + cc * 32 + icl) * 3 + ky) * 3 + kx]);
    return;
  }
  j -= 82944;
  if (j < 9216) { P[i] = f2bf(c3w[j]); return; }
  j -= 9216;
  if (j < 36864) { P[i] = f2bf(Win[j]); return; }
  j -= 36864;
  if (j < 9216) {
    int oc = j / 192, k = j - oc * 192;
    P[i] = (oc < 38) ? f2bf(Wx[oc * 192 + k]) : (unsigned short)0;
    return;
  }
  j -= 9216;
  P[i] = f2bf(Wout[j]);
}

// ---------------- bilinear upsample 2x ----------------
__global__ __launch_bounds__(256) void k_upsample(const float* __restrict__ x, float* __restrict__ up) {
  int idx = blockIdx.x * 256 + threadIdx.x;
  if (idx >= 2 * 96 * LSEQ) return;
  int ow = idx & 127, oh = (idx >> 7) & 127, bc = idx >> 14;
  float pr = oh * (63.0f / 127.0f); int r0 = (int)pr; float rw = pr - (float)r0; int r1 = min(r0 + 1, 63);
  float pc = ow * (63.0f / 127.0f); int c0 = (int)pc; float cw = pc - (float)c0; int c1 = min(c0 + 1, 63);
  const float* xp = x + (size_t)bc * 4096;
  float v00 = xp[r0 * 64 + c0], v01 = xp[r0 * 64 + c1];
  float v10 = xp[r1 * 64 + c0], v11 = xp[r1 * 64 + c1];
  float top = v00 + (v10 - v00) * rw;
  float bot = v01 + (v11 - v01) * rw;
  up[idx] = top + (bot - top) * cw;
}

// ---------------- generic MFMA GEMM ----------------
#define SRC_PLANAR2 0
#define SRC_ROWS    1
#define OUT_BF16R    0
#define OUT_F32P     1
#define OUT_F32R     2
#define OUT_F32P_RES 4
#define OUT_XZ       5   // groups 0-1 -> f32 rows192 (outv), 2-3 -> bf16 rows192 (outv2)

template<int SM, int OM, int NT>
__global__ __launch_bounds__(256) void k_gemm(
    const void* __restrict__ xa, const void* __restrict__ xb, int CA,
    const unsigned short* __restrict__ Wp, const float* __restrict__ bias,
    void* __restrict__ outv, void* __restrict__ outv2, const float* __restrict__ resid,
    int K, int ostride, int ng) {
  __shared__ unsigned short x_t[128 * 96];
  __shared__ unsigned short w_t[NT * 16 * 96];
  Wp += (size_t)blockIdx.y * 96 * K;
  int pxg0 = blockIdx.x * 128;
  int b = pxg0 >> 14, px_in0 = pxg0 & 16383;
  int tid = threadIdx.x, lane = tid & 63, wv = tid >> 6;
  int r = lane & 15, q = lane >> 4;
  f4v acc[2][NT];
#pragma unroll
  for (int mi = 0; mi < 2; mi++)
#pragma unroll
    for (int n = 0; n < NT; n++) acc[mi][n] = (f4v)0.0f;
  int nchunk = K / 96;
  for (int kc = 0; kc < nchunk; kc++) {
    for (int t = tid; t < NT * 16 * 12; t += 256) {
      int row = t / 12, u8 = t - row * 12;
      *(u16x8*)&w_t[row * 96 + u8 * 8] = *(const u16x8*)&Wp[(size_t)row * K + kc * 96 + u8 * 8];
    }
    if (SM == SRC_PLANAR2) {
      const float* A0 = (const float*)xa;
      const float* A1 = (const float*)xb;
      int CB = K - CA;
      for (int t = tid; t < 3072; t += 256) {
        int px4 = t / 96, c_l = t - px4 * 96;
        int c = kc * 96 + c_l;
        const float* sp = (c < CA) ? (A0 + ((size_t)b * CA + c) * LSEQ + px_in0 + px4 * 4)
                                   : (A1 + ((size_t)b * CB + (c - CA)) * LSEQ + px_in0 + px4 * 4);
        float4 v = *(const float4*)sp;
        x_t[(px4 * 4 + 0) * 96 + c_l] = f2bf(v.x);
        x_t[(px4 * 4 + 1) * 96 + c_l] = f2bf(v.y);
        x_t[(px4 * 4 + 2) * 96 + c_l] = f2bf(v.z);
        x_t[(px4 * 4 + 3) * 96 + c_l] = f2bf(v.w);
      }
    } else {
      const unsigned short* X = (const unsigned short*)xa;
      for (int t = tid; t < 1536; t += 256) {
        int rr = t / 12, u8 = t - rr * 12;
        *(u16x8*)&x_t[rr * 96 + u8 * 8] =
            *(const u16x8*)&X[(size_t)(pxg0 + rr) * K + kc * 96 + u8 * 8];
      }
    }
    __syncthreads();
#pragma unroll
    for (int k0 = 0; k0 < 96; k0 += 32) {
      s8v a0 = *(const s8v*)&x_t[((wv * 2 + 0) * 16 + r) * 96 + k0 + q * 8];
      s8v a1 = *(const s8v*)&x_t[((wv * 2 + 1) * 16 + r) * 96 + k0 + q * 8];
#pragma unroll
      for (int n = 0; n < NT; n++) {
        s8v bb = *(const s8v*)&w_t[(n * 16 + r) * 96 + k0 + q * 8];
        acc[0][n] = __builtin_amdgcn_mfma_f32_16x16x32_bf16(a0, bb, acc[0][n], 0, 0, 0);
        acc[1][n] = __builtin_amdgcn_mfma_f32_16x16x32_bf16(a1, bb, acc[1][n], 0, 0, 0);
      }
    }
    __syncthreads();
  }
#pragma unroll
  for (int mi = 0; mi < 2; mi++) {
    int pxl = (wv * 2 + mi) * 16 + q * 4;
    int pxg = pxg0 + pxl;
#pragma unroll
    for (int n = 0; n < NT; n++) {
      int oc = n * 16 + r;
      if (OM == OUT_BF16R) {
        float bv = bias[oc];
        unsigned short* O = (unsigned short*)outv;
#pragma unroll
        for (int g = 0; g < 4; g++)
          O[(size_t)(pxg + g) * 96 + oc] = f2bf(acc[mi][n][g] + bv);
      } else if (OM == OUT_F32P) {
        float bv = bias[oc];
        float* O = (float*)outv;
        float4 o = make_float4(acc[mi][n][0] + bv, acc[mi][n][1] + bv,
                               acc[mi][n][2] + bv, acc[mi][n][3] + bv);
        *(float4*)&O[((size_t)b * 96 + oc) * LSEQ + px_in0 + pxl] = o;
      } else if (OM == OUT_F32P_RES) {
        float* O = (float*)outv;
        size_t ad = ((size_t)b * 96 + oc) * LSEQ + px_in0 + pxl;
        float4 rv = *(const float4*)&resid[ad];
        float4 o = make_float4(acc[mi][n][0] + rv.x, acc[mi][n][1] + rv.y,
                               acc[mi][n][2] + rv.z, acc[mi][n][3] + rv.w);
        *(float4*)&O[ad] = o;
      } else if (OM == OUT_F32R) {
        float* O = (float*)outv;
        int ocg = blockIdx.y * 96 + oc;
        if (ocg < ng) {
#pragma unroll
          for (int g = 0; g < 4; g++)
            O[(size_t)(pxg + g) * ostride + ocg] = acc[mi][n][g];
        }
      } else { // OUT_XZ
        int ocg = (blockIdx.y & 1) * 96 + oc;
        if (blockIdx.y < 2) {
          float* O = (float*)outv;
#pragma unroll
          for (int g = 0; g < 4; g++)
            O[(size_t)(pxg + g) * 192 + ocg] = acc[mi][n][g];
        } else {
          unsigned short* O = (unsigned short*)outv2;
#pragma unroll
          for (int g = 0; g < 4; g++)
            O[(size_t)(pxg + g) * 192 + ocg] = f2bf(acc[mi][n][g]);
        }
      }
    }
  }
}

// ---------------- conv3x3 implicit-GEMM MFMA ----------------
__global__ __launch_bounds__(256) void k_conv3x3m(const unsigned short* __restrict__ X,
    const unsigned short* __restrict__ Wp2, const float* __restrict__ bias,
    unsigned short* __restrict__ out) {
  __shared__ unsigned short in_t[3 * 68 * 32];
  __shared__ unsigned short w_t[9 * 96 * 32];
  int bi = blockIdx.x;
  int hx = bi & 1, y = (bi >> 1) & 127, b = bi >> 8;
  int px0 = hx * 64;
  int tid = threadIdx.x, lane = tid & 63, wv = tid >> 6;
  int r = lane & 15, q = lane >> 4;
  f4v acc[6];
#pragma unroll
  for (int n = 0; n < 6; n++) acc[n] = (f4v)0.0f;
  for (int cc = 0; cc < 3; cc++) {
    for (int t = tid; t < 3456; t += 256)
      *(u16x8*)&w_t[t * 8] = *(const u16x8*)&Wp2[cc * 27648 + t * 8];
    for (int t = tid; t < 792; t += 256) {
      int row = t / 264, rem = t - row * 264;
      int c_l = rem >> 2, icq = rem & 3;
      int gy = y - 1 + row, gx = px0 - 1 + c_l;
      u16x8 v = {0, 0, 0, 0, 0, 0, 0, 0};
      if (gy >= 0 && gy < 128 && gx >= 0 && gx < 128)
        v = *(const u16x8*)&X[(((size_t)b * 128 + gy) * 128 + gx) * 96 + cc * 32 + icq * 8];
      *(u16x8*)&in_t[(row * 68 + c_l) * 32 + icq * 8] = v;
    }
    __syncthreads();
#pragma unroll
    for (int kk = 0; kk < 9; kk++) {
      int ky = kk / 3, kx = kk - ky * 3;
      s8v a = *(const s8v*)&in_t[(ky * 68 + wv * 16 + r + kx) * 32 + q * 8];
#pragma unroll
      for (int n = 0; n < 6; n++) {
        s8v bb = *(const s8v*)&w_t[(kk * 96 + n * 16 + r) * 32 + q * 8];
        acc[n] = __builtin_amdgcn_mfma_f32_16x16x32_bf16(a, bb, acc[n], 0, 0, 0);
      }
    }
    __syncthreads();
  }
  size_t rowbase = ((size_t)b * 128 + y) * 128 + px0 + wv * 16 + q * 4;
#pragma unroll
  for (int n = 0; n < 6; n++) {
    int oc = n * 16 + r;
    float bv = bias[oc];
#pragma unroll
    for (int g = 0; g < 4; g++)
      out[(rowbase + g) * 96 + oc] = f2bf(acc[n][g] + bv);
  }
}

// ---------------- instance-norm stats ----------------
__global__ __launch_bounds__(256) void k_stats(const float* __restrict__ h, float* __restrict__ stats) {
  int bc = blockIdx.x;
  const float* p = h + (size_t)bc * LSEQ;
  float s = 0.f, ss = 0.f;
  for (int i = threadIdx.x; i < LSEQ; i += 256) { float v = p[i]; s += v; ss = fmaf(v, v, ss); }
  __shared__ float rs[256], rss[256];
  int tid = threadIdx.x;
  rs[tid] = s; rss[tid] = ss; __syncthreads();
  for (int o = 128; o > 0; o >>= 1) {
    if (tid < o) { rs[tid] += rs[tid + o]; rss[tid] += rss[tid + o]; }
    __syncthreads();
  }
  if (tid == 0) {
    float m = rs[0] * (1.0f / LSEQ);
    float var = rss[0] * (1.0f / LSEQ) - m * m;
    stats[bc * 2] = m;
    stats[bc * 2 + 1] = rsqrtf(fmaxf(var, 0.f) + 1e-5f);
  }
}

// ---------------- normalize + SELU ----------------
__global__ __launch_bounds__(256) void k_normselu2(const float* __restrict__ h,
    const float* __restrict__ stats, float* __restrict__ Lx, unsigned short* __restrict__ LxR) {
  __shared__ float tile[96 * 65];
  int px0 = blockIdx.x * 64, b = blockIdx.y;
  int tid = threadIdx.x;
  const float kS = 1.0507009873554805f, kA = 1.6732632423543772f;
  for (int t = tid; t < 1536; t += 256) {
    int c = t >> 4, p4 = t & 15;
    size_t ga = ((size_t)b * 96 + c) * LSEQ + px0 + p4 * 4;
    float4 v = *(const float4*)&h[ga];
    float m = stats[(b * 96 + c) * 2], rv = stats[(b * 96 + c) * 2 + 1];
    v.x = (v.x - m) * rv; v.y = (v.y - m) * rv; v.z = (v.z - m) * rv; v.w = (v.w - m) * rv;
    v.x = v.x > 0.f ? kS * v.x : kS * kA * expm1f(v.x);
    v.y = v.y > 0.f ? kS * v.y : kS * kA * expm1f(v.y);
    v.z = v.z > 0.f ? kS * v.z : kS * kA * expm1f(v.z);
    v.w = v.w > 0.f ? kS * v.w : kS * kA * expm1f(v.w);
    *(float4*)&Lx[ga] = v;
    tile[c * 65 + p4 * 4 + 0] = v.x;
    tile[c * 65 + p4 * 4 + 1] = v.y;
    tile[c * 65 + p4 * 4 + 2] = v.z;
    tile[c * 65 + p4 * 4 + 3] = v.w;
  }
  __syncthreads();
  for (int t = tid; t < 768; t += 256) {
    int px = t / 12, c8 = t - px * 12;
    u16x8 o;
#pragma unroll
    for (int jj = 0; jj < 8; jj++) o[jj] = f2bf(tile[(c8 * 8 + jj) * 65 + px]);
    *(u16x8*)&LxR[((size_t)b * LSEQ + px0 + px) * 96 + c8 * 8] = o;
  }
}

// ---------------- causal depthwise conv1d + SiLU ----------------
__global__ __launch_bounds__(256) void k_conv1d(const float* __restrict__ xzx,
    const float* __restrict__ w1d, const float* __restrict__ b1d,
    float* __restrict__ u, unsigned short* __restrict__ uR) {
  int gid = blockIdx.x * 256 + threadIdx.x;
  if (gid >= 2 * LSEQ * DIN) return;
  int d = gid % DIN, bl = gid / DIN;
  int l = bl & (LSEQ - 1);
  float4 w = *(const float4*)&w1d[d * 4];
  float wv[4] = {w.x, w.y, w.z, w.w};
  float acc = b1d[d];
#pragma unroll
  for (int k = 0; k < 4; k++) {
    int lk = l - 3 + k;
    if (lk >= 0) acc = fmaf(wv[k], xzx[(size_t)(bl - 3 + k) * DIN + d], acc);
  }
  float s = siluf(acc);
  u[gid] = s;
  uR[gid] = f2bf(s);
}

// ---------------- scan phase A: per-chunk (prod a, h_end), dt fused ----------------
__global__ __launch_bounds__(192) void k_scanA(const float* __restrict__ u,
    const float* __restrict__ xdbl, const float* __restrict__ Wdt,
    const float* __restrict__ bdt, const float* __restrict__ Alog,
    float* __restrict__ chA, float* __restrict__ chB) {
  int b = blockIdx.y, g = blockIdx.x, d = threadIdx.x;
  __shared__ float Bs[TCH * 16], Dts[TCH * 8];
  for (int i = d; i < TCH * 16; i += 192) {
    int t = i >> 4, n = i & 15;
    Bs[i] = xdbl[(size_t)(b * LSEQ + g * TCH + t) * 38 + 6 + n];
  }
  for (int i = d; i < TCH * 6; i += 192) {
    int t = i / 6, c = i - t * 6;
    Dts[t * 8 + c] = xdbl[(size_t)(b * LSEQ + g * TCH + t) * 38 + c];
  }
  float ac[16];
#pragma unroll
  for (int n = 0; n < 16; n++) ac[n] = -__expf(Alog[d * 16 + n]);
  float wdt[6];
#pragma unroll
  for (int c = 0; c < 6; c++) wdt[c] = Wdt[d * 6 + c];
  float bd = bdt[d];
  __syncthreads();
  float ap[16], hb[16];
#pragma unroll
  for (int n = 0; n < 16; n++) { ap[n] = 1.f; hb[n] = 0.f; }
  for (int t = 0; t < TCH; t++) {
    size_t base = (size_t)(b * LSEQ + g * TCH + t);
    float uv = u[base * DIN + d];
    float dtraw = bd;
#pragma unroll
    for (int c = 0; c < 6; c++) dtraw = fmaf(Dts[t * 8 + c], wdt[c], dtraw);
    float dtv = dtraw > 20.f ? dtraw : log1pf(__expf(dtraw));
    float du = dtv * uv;
    float bs[16];
    const float4* src = (const float4*)&Bs[t * 16];
#pragma unroll
    for (int qq = 0; qq < 4; qq++) {
      float4 v = src[qq];
      bs[qq * 4] = v.x; bs[qq * 4 + 1] = v.y; bs[qq * 4 + 2] = v.z; bs[qq * 4 + 3] = v.w;
    }
#pragma unroll
    for (int n = 0; n < 16; n++) {
      float e = __expf(dtv * ac[n]);
      ap[n] *= e;
      hb[n] = fmaf(hb[n], e, du * bs[n]);
    }
  }
  size_t co = ((size_t)(b * GCH + g) * DIN + d) * 16;
#pragma unroll
  for (int qq = 0; qq < 4; qq++) {
    ((float4*)(chA + co))[qq] = make_float4(ap[qq * 4], ap[qq * 4 + 1], ap[qq * 4 + 2], ap[qq * 4 + 3]);
    ((float4*)(chB + co))[qq] = make_float4(hb[qq * 4], hb[qq * 4 + 1], hb[qq * 4 + 2], hb[qq * 4 + 3]);
  }
}

// ---------------- scan phase B ----------------
__global__ __launch_bounds__(256) void k_scanB(const float* __restrict__ chA,
    const float* __restrict__ chB, float* __restrict__ h0) {
  int tid = blockIdx.x * 256 + threadIdx.x;
  if (tid >= 2 * DIN * 16) return;
  int b = tid / (DIN * 16), rem = tid - b * DIN * 16;
  float h = 0.f;
#pragma unroll 4
  for (int g = 0; g < GCH; g++) {
    size_t off = (size_t)(b * GCH + g) * (DIN * 16) + rem;
    h0[off] = h;
    h = fmaf(h, chA[off], chB[off]);
  }
}

// ---------------- scan phase C: replay + gate, dt fused ----------------
__global__ __launch_bounds__(192) void k_scanC(const float* __restrict__ u,
    const float* __restrict__ xdbl, const float* __restrict__ Wdt,
    const float* __restrict__ bdt, const unsigned short* __restrict__ zR,
    const float* __restrict__ Alog, const float* __restrict__ Dp,
    const float* __restrict__ h0, unsigned short* __restrict__ yR) {
  int b = blockIdx.y, g = blockIdx.x, d = threadIdx.x;
  __shared__ float Bs[TCH * 16], Cs[TCH * 16], Dts[TCH * 8];
  for (int i = d; i < TCH * 16; i += 192) {
    int t = i >> 4, n = i & 15;
    size_t rb = (size_t)(b * LSEQ + g * TCH + t) * 38;
    Bs[i] = xdbl[rb + 6 + n];
    Cs[i] = xdbl[rb + 22 + n];
  }
  for (int i = d; i < TCH * 6; i += 192) {
    int t = i / 6, c = i - t * 6;
    Dts[t * 8 + c] = xdbl[(size_t)(b * LSEQ + g * TCH + t) * 38 + c];
  }
  float ac[16];
#pragma unroll
  for (int n = 0; n < 16; n++) ac[n] = -__expf(Alog[d * 16 + n]);
  float wdt[6];
#pragma unroll
  for (int c = 0; c < 6; c++) wdt[c] = Wdt[d * 6 + c];
  float bd = bdt[d];
  float Dd = Dp[d];
  __syncthreads();
  size_t co = ((size_t)(b * GCH + g) * DIN + d) * 16;
  float h[16];
#pragma unroll
  for (int qq = 0; qq < 4; qq++) {
    float4 v = ((const float4*)(h0 + co))[qq];
    h[qq * 4] = v.x; h[qq * 4 + 1] = v.y; h[qq * 4 + 2] = v.z; h[qq * 4 + 3] = v.w;
  }
  for (int t = 0; t < TCH; t++) {
    size_t base = (size_t)(b * LSEQ + g * TCH + t);
    float uv = u[base * DIN + d];
    float zv = bf2f(zR[base * DIN + d]);
    float dtraw = bd;
#pragma unroll
    for (int c = 0; c < 6; c++) dtraw = fmaf(Dts[t * 8 + c], wdt[c], dtraw);
    float dtv = dtraw > 20.f ? dtraw : log1pf(__expf(dtraw));
    float du = dtv * uv;
    float bs[16], cs[16];
    const float4* sb = (const float4*)&Bs[t * 16];
    const float4* sc = (const float4*)&Cs[t * 16];
#pragma unroll
    for (int qq = 0; qq < 4; qq++) {
      float4 vb = sb[qq], vc = sc[qq];
      bs[qq * 4] = vb.x; bs[qq * 4 + 1] = vb.y; bs[qq * 4 + 2] = vb.z; bs[qq * 4 + 3] = vb.w;
      cs[qq * 4] = vc.x; cs[qq * 4 + 1] = vc.y; cs[qq * 4 + 2] = vc.z; cs[qq * 4 + 3] = vc.w;
    }
    float y0 = 0.f, y1 = 0.f, y2 = 0.f, y3 = 0.f;
#pragma unroll
    for (int n = 0; n < 16; n++) {
      float e = __expf(dtv * ac[n]);
      h[n] = fmaf(h[n], e, du * bs[n]);
      float p = h[n] * cs[n];
      if ((n & 3) == 0) y0 += p; else if ((n & 3) == 1) y1 += p;
      else if ((n & 3) == 2) y2 += p; else y3 += p;
    }
    float yv = ((y0 + y1) + (y2 + y3)) + uv * Dd;
    yR[base * DIN + d] = f2bf(yv * siluf(zv));
  }
}

// ---------------- launch ----------------
extern "C" void kernel_launch(void* const* d_in, const int* in_sizes, int n_in,
                              void* d_out, int out_size, void* d_ws, size_t ws_size,
                              hipStream_t stream) {
  (void)in_sizes; (void)n_in; (void)out_size; (void)ws_size;
  const float* x    = (const float*)d_in[0];
  const float* Hx   = (const float*)d_in[1];
  const float* c1w  = (const float*)d_in[2];
  const float* c1b  = (const float*)d_in[3];
  const float* c2w  = (const float*)d_in[4];
  const float* c2b  = (const float*)d_in[5];
  const float* c3w  = (const float*)d_in[6];
  const float* c3b  = (const float*)d_in[7];
  const float* Win  = (const float*)d_in[8];
  const float* w1d  = (const float*)d_in[9];
  const float* b1d  = (const float*)d_in[10];
  const float* Wx   = (const float*)d_in[11];
  const float* Wdt  = (const float*)d_in[12];
  const float* bdt  = (const float*)d_in[13];
  const float* Alog = (const float*)d_in[14];
  const float* Dp   = (const float*)d_in[15];
  const float* Wout = (const float*)d_in[16];
  float* out = (float*)d_out;

  float* ws = (float*)d_ws;
  const size_t F = (size_t)2 * 96 * LSEQ;      // 3,145,728 floats
  const size_t Fh = F / 2;

  // R6 layout (floats), total 9F + 92,544 ~= 108.6 MB:
  //  [0,F)      up -> h3 -> chA           (h3 dead after normselu2; chA: scanA->scanB)
  //  [F,2F)     Lx f32 planar             (normselu2 -> outproj)
  //  [2F,2.5F)  R1: h1 rows96 -> LxR rows96 (dead after inproj)
  //  [2.5F,3F)  R2: h2 rows96 (dead after conv3-1x1) -> xdbl f32 rows38 (XDBL<Fh)
  //  [3F,5F)    xzx f32 rows192 (dead after conv1d) -> chB [3F,4F) + h0 [4F,5F)
  //  [5F,6F)    zR bf16 rows192 (inproj -> scanC)
  //  [6F,7F)    R3: uR rows192 (conv1d -> xproj) -> yR rows192 (scanC -> outproj)
  //  [7F,9F)    u f32 rows192 (conv1d -> scanC)
  //  [9F,...]   Wp (92160) + stats (384)
  float*          b_up = ws;
  float*          b_h3 = ws;
  float*          chA  = ws;
  float*          b_Lx = ws + F;
  unsigned short* R1   = (unsigned short*)(ws + 2 * F);
  unsigned short* R2   = (unsigned short*)(ws + 2 * F + Fh);
  float*          xdbl = ws + 2 * F + Fh;
  float*          xzx  = ws + 3 * F;
  float*          chB  = ws + 3 * F;
  float*          h0b  = ws + 4 * F;
  unsigned short* zRb  = (unsigned short*)(ws + 5 * F);
  unsigned short* R3   = (unsigned short*)(ws + 6 * F);
  float*          b_u  = ws + 7 * F;
  unsigned short* Wp   = (unsigned short*)(ws + 9 * F);
  float*          b_st = ws + 9 * F + 92160;

  k_packw<<<dim3(720), dim3(256), 0, stream>>>(c1w, c2w, c3w, Win, Wx, Wout, Wp);
  k_upsample<<<dim3(12288), dim3(256), 0, stream>>>(x, b_up);
  k_gemm<SRC_PLANAR2, OUT_BF16R, 6><<<dim3(256, 1), dim3(256), 0, stream>>>(
      b_up, Hx, 96, Wp, c1b, R1, nullptr, nullptr, 288, 0, 0);
  k_conv3x3m<<<dim3(512), dim3(256), 0, stream>>>(R1, Wp + 27648, c2b, R2);
  k_gemm<SRC_ROWS, OUT_F32P, 6><<<dim3(256, 1), dim3(256), 0, stream>>>(
      R2, nullptr, 0, Wp + 110592, c3b, b_h3, nullptr, nullptr, 96, 0, 0);
  k_stats<<<dim3(192), dim3(256), 0, stream>>>(b_h3, b_st);
  k_normselu2<<<dim3(256, 2), dim3(256), 0, stream>>>(b_h3, b_st, b_Lx, R1);
  // in_proj merged: groups 0-1 -> xzx f32 rows192, groups 2-3 -> zR bf16 rows192
  k_gemm<SRC_ROWS, OUT_XZ, 6><<<dim3(256, 4), dim3(256), 0, stream>>>(
      R1, nullptr, 0, Wp + 119808, nullptr, xzx, zRb, nullptr, 96, 192, 0);
  k_conv1d<<<dim3((2 * LSEQ * DIN + 255) / 256), dim3(256), 0, stream>>>(xzx, w1d, b1d, b_u, R3);
  k_gemm<SRC_ROWS, OUT_F32R, 3><<<dim3(256, 1), dim3(256), 0, stream>>>(
      R3, nullptr, 0, Wp + 156672, nullptr, xdbl, nullptr, nullptr, 192, 38, 38);
  k_scanA<<<dim3(GCH, 2), dim3(192), 0, stream>>>(b_u, xdbl, Wdt, bdt, Alog, chA, chB);
  k_scanB<<<dim3(24), dim3(256), 0, stream>>>(chA, chB, h0b);
  k_scanC<<<dim3(GCH, 2), dim3(192), 0, stream>>>(b_u, xdbl, Wdt, bdt, zRb, Alog, Dp, h0b, R3);
  k_gemm<SRC_ROWS, OUT_F32P_RES, 6><<<dim3(256, 1), dim3(256), 0, stream>>>(
      R3, nullptr, 0, Wp + 165888, nullptr, out, nullptr, b_Lx, 192, 0, 0);
}

// Round 7
// 380.602 us; speedup vs baseline: 1.1191x; 1.1191x over previous
//
#include <hip/hip_runtime.h>
#include <hip/hip_bf16.h>
#include <math.h>

#define LSEQ 16384
#define DIN  192
#define GCH  512
#define TCH  32

typedef float f4v __attribute__((ext_vector_type(4)));
typedef short s8v __attribute__((ext_vector_type(8)));
typedef unsigned short u16x8 __attribute__((ext_vector_type(8)));

__device__ __forceinline__ float siluf(float x) { return x / (1.0f + __expf(-x)); }
__device__ __forceinline__ unsigned short f2bf(float f) {
  unsigned int u = __float_as_uint(f);
  unsigned int r = (u + 0x7FFFu + ((u >> 16) & 1u)) >> 16;
  return (unsigned short)r;
}
__device__ __forceinline__ float bf2f(unsigned short s) {
  return __uint_as_float(((unsigned int)s) << 16);
}

// ---------------- weight pre-pack to bf16 ----------------
__global__ __launch_bounds__(256) void k_packw(const float* __restrict__ c1w,
    const float* __restrict__ c2w, const float* __restrict__ c3w,
    const float* __restrict__ Win, const float* __restrict__ Wx,
    const float* __restrict__ Wout, unsigned short* __restrict__ P) {
  int i = blockIdx.x * 256 + threadIdx.x;
  if (i >= 184320) return;
  if (i < 27648) { P[i] = f2bf(c1w[i]); return; }
  int j = i - 27648;
  if (j < 82944) {
    int cc = j / 27648, r = j - cc * 27648;
    int kk = r / 3072, r2 = r - kk * 3072;
    int oc = r2 >> 5, icl = r2 & 31;
    int ky = kk / 3, kx = kk - ky * 3;
    P[i] = f2bf(c2w[((oc * 96 + cc * 32 + icl) * 3 + ky) * 3 + kx]);
    return;
  }
  j -= 82944;
  if (j < 9216) { P[i] = f2bf(c3w[j]); return; }
  j -= 9216;
  if (j < 36864) { P[i] = f2bf(Win[j]); return; }
  j -= 36864;
  if (j < 9216) {
    int oc = j / 192, k = j - oc * 192;
    P[i] = (oc < 38) ? f2bf(Wx[oc * 192 + k]) : (unsigned short)0;
    return;
  }
  j -= 9216;
  P[i] = f2bf(Wout[j]);
}

// ---------------- bilinear upsample 2x ----------------
__global__ __launch_bounds__(256) void k_upsample(const float* __restrict__ x, float* __restrict__ up) {
  int idx = blockIdx.x * 256 + threadIdx.x;
  if (idx >= 2 * 96 * LSEQ) return;
  int ow = idx & 127, oh = (idx >> 7) & 127, bc = idx >> 14;
  float pr = oh * (63.0f / 127.0f); int r0 = (int)pr; float rw = pr - (float)r0; int r1 = min(r0 + 1, 63);
  float pc = ow * (63.0f / 127.0f); int c0 = (int)pc; float cw = pc - (float)c0; int c1 = min(c0 + 1, 63);
  const float* xp = x + (size_t)bc * 4096;
  float v00 = xp[r0 * 64 + c0], v01 = xp[r0 * 64 + c1];
  float v10 = xp[r1 * 64 + c0], v11 = xp[r1 * 64 + c1];
  float top = v00 + (v10 - v00) * rw;
  float bot = v01 + (v11 - v01) * rw;
  up[idx] = top + (bot - top) * cw;
}

// ---------------- generic MFMA GEMM ----------------
#define SRC_PLANAR2 0
#define SRC_ROWS    1
#define OUT_BF16R    0
#define OUT_F32P     1
#define OUT_F32R     2
#define OUT_F32P_RES 4
#define OUT_XZ       5

template<int SM, int OM, int NT>
__global__ __launch_bounds__(256) void k_gemm(
    const void* __restrict__ xa, const void* __restrict__ xb, int CA,
    const unsigned short* __restrict__ Wp, const float* __restrict__ bias,
    void* __restrict__ outv, void* __restrict__ outv2, const float* __restrict__ resid,
    int K, int ostride, int ng) {
  __shared__ unsigned short x_t[128 * 96];
  __shared__ unsigned short w_t[NT * 16 * 96];
  Wp += (size_t)blockIdx.y * 96 * K;
  int pxg0 = blockIdx.x * 128;
  int b = pxg0 >> 14, px_in0 = pxg0 & 16383;
  int tid = threadIdx.x, lane = tid & 63, wv = tid >> 6;
  int r = lane & 15, q = lane >> 4;
  f4v acc[2][NT];
#pragma unroll
  for (int mi = 0; mi < 2; mi++)
#pragma unroll
    for (int n = 0; n < NT; n++) acc[mi][n] = (f4v)0.0f;
  int nchunk = K / 96;
  for (int kc = 0; kc < nchunk; kc++) {
    for (int t = tid; t < NT * 16 * 12; t += 256) {
      int row = t / 12, u8 = t - row * 12;
      *(u16x8*)&w_t[row * 96 + u8 * 8] = *(const u16x8*)&Wp[(size_t)row * K + kc * 96 + u8 * 8];
    }
    if (SM == SRC_PLANAR2) {
      const float* A0 = (const float*)xa;
      const float* A1 = (const float*)xb;
      int CB = K - CA;
      for (int t = tid; t < 3072; t += 256) {
        int px4 = t / 96, c_l = t - px4 * 96;
        int c = kc * 96 + c_l;
        const float* sp = (c < CA) ? (A0 + ((size_t)b * CA + c) * LSEQ + px_in0 + px4 * 4)
                                   : (A1 + ((size_t)b * CB + (c - CA)) * LSEQ + px_in0 + px4 * 4);
        float4 v = *(const float4*)sp;
        x_t[(px4 * 4 + 0) * 96 + c_l] = f2bf(v.x);
        x_t[(px4 * 4 + 1) * 96 + c_l] = f2bf(v.y);
        x_t[(px4 * 4 + 2) * 96 + c_l] = f2bf(v.z);
        x_t[(px4 * 4 + 3) * 96 + c_l] = f2bf(v.w);
      }
    } else {
      const unsigned short* X = (const unsigned short*)xa;
      for (int t = tid; t < 1536; t += 256) {
        int rr = t / 12, u8 = t - rr * 12;
        *(u16x8*)&x_t[rr * 96 + u8 * 8] =
            *(const u16x8*)&X[(size_t)(pxg0 + rr) * K + kc * 96 + u8 * 8];
      }
    }
    __syncthreads();
#pragma unroll
    for (int k0 = 0; k0 < 96; k0 += 32) {
      s8v a0 = *(const s8v*)&x_t[((wv * 2 + 0) * 16 + r) * 96 + k0 + q * 8];
      s8v a1 = *(const s8v*)&x_t[((wv * 2 + 1) * 16 + r) * 96 + k0 + q * 8];
#pragma unroll
      for (int n = 0; n < NT; n++) {
        s8v bb = *(const s8v*)&w_t[(n * 16 + r) * 96 + k0 + q * 8];
        acc[0][n] = __builtin_amdgcn_mfma_f32_16x16x32_bf16(a0, bb, acc[0][n], 0, 0, 0);
        acc[1][n] = __builtin_amdgcn_mfma_f32_16x16x32_bf16(a1, bb, acc[1][n], 0, 0, 0);
      }
    }
    __syncthreads();
  }
#pragma unroll
  for (int mi = 0; mi < 2; mi++) {
    int pxl = (wv * 2 + mi) * 16 + q * 4;
    int pxg = pxg0 + pxl;
#pragma unroll
    for (int n = 0; n < NT; n++) {
      int oc = n * 16 + r;
      if (OM == OUT_BF16R) {
        float bv = bias[oc];
        unsigned short* O = (unsigned short*)outv;
#pragma unroll
        for (int g = 0; g < 4; g++)
          O[(size_t)(pxg + g) * 96 + oc] = f2bf(acc[mi][n][g] + bv);
      } else if (OM == OUT_F32P) {
        float bv = bias[oc];
        float* O = (float*)outv;
        float4 o = make_float4(acc[mi][n][0] + bv, acc[mi][n][1] + bv,
                               acc[mi][n][2] + bv, acc[mi][n][3] + bv);
        *(float4*)&O[((size_t)b * 96 + oc) * LSEQ + px_in0 + pxl] = o;
      } else if (OM == OUT_F32P_RES) {
        float* O = (float*)outv;
        size_t ad = ((size_t)b * 96 + oc) * LSEQ + px_in0 + pxl;
        float4 rv = *(const float4*)&resid[ad];
        float4 o = make_float4(acc[mi][n][0] + rv.x, acc[mi][n][1] + rv.y,
                               acc[mi][n][2] + rv.z, acc[mi][n][3] + rv.w);
        *(float4*)&O[ad] = o;
      } else if (OM == OUT_F32R) {
        float* O = (float*)outv;
        int ocg = blockIdx.y * 96 + oc;
        if (ocg < ng) {
#pragma unroll
          for (int g = 0; g < 4; g++)
            O[(size_t)(pxg + g) * ostride + ocg] = acc[mi][n][g];
        }
      } else { // OUT_XZ
        int ocg = (blockIdx.y & 1) * 96 + oc;
        if (blockIdx.y < 2) {
          float* O = (float*)outv;
#pragma unroll
          for (int g = 0; g < 4; g++)
            O[(size_t)(pxg + g) * 192 + ocg] = acc[mi][n][g];
        } else {
          unsigned short* O = (unsigned short*)outv2;
#pragma unroll
          for (int g = 0; g < 4; g++)
            O[(size_t)(pxg + g) * 192 + ocg] = f2bf(acc[mi][n][g]);
        }
      }
    }
  }
}

// ---------------- conv3x3 implicit-GEMM MFMA ----------------
__global__ __launch_bounds__(256) void k_conv3x3m(const unsigned short* __restrict__ X,
    const unsigned short* __restrict__ Wp2, const float* __restrict__ bias,
    unsigned short* __restrict__ out) {
  __shared__ unsigned short in_t[3 * 68 * 32];
  __shared__ unsigned short w_t[9 * 96 * 32];
  int bi = blockIdx.x;
  int hx = bi & 1, y = (bi >> 1) & 127, b = bi >> 8;
  int px0 = hx * 64;
  int tid = threadIdx.x, lane = tid & 63, wv = tid >> 6;
  int r = lane & 15, q = lane >> 4;
  f4v acc[6];
#pragma unroll
  for (int n = 0; n < 6; n++) acc[n] = (f4v)0.0f;
  for (int cc = 0; cc < 3; cc++) {
    for (int t = tid; t < 3456; t += 256)
      *(u16x8*)&w_t[t * 8] = *(const u16x8*)&Wp2[cc * 27648 + t * 8];
    for (int t = tid; t < 792; t += 256) {
      int row = t / 264, rem = t - row * 264;
      int c_l = rem >> 2, icq = rem & 3;
      int gy = y - 1 + row, gx = px0 - 1 + c_l;
      u16x8 v = {0, 0, 0, 0, 0, 0, 0, 0};
      if (gy >= 0 && gy < 128 && gx >= 0 && gx < 128)
        v = *(const u16x8*)&X[(((size_t)b * 128 + gy) * 128 + gx) * 96 + cc * 32 + icq * 8];
      *(u16x8*)&in_t[(row * 68 + c_l) * 32 + icq * 8] = v;
    }
    __syncthreads();
#pragma unroll
    for (int kk = 0; kk < 9; kk++) {
      int ky = kk / 3, kx = kk - ky * 3;
      s8v a = *(const s8v*)&in_t[(ky * 68 + wv * 16 + r + kx) * 32 + q * 8];
#pragma unroll
      for (int n = 0; n < 6; n++) {
        s8v bb = *(const s8v*)&w_t[(kk * 96 + n * 16 + r) * 32 + q * 8];
        acc[n] = __builtin_amdgcn_mfma_f32_16x16x32_bf16(a, bb, acc[n], 0, 0, 0);
      }
    }
    __syncthreads();
  }
  size_t rowbase = ((size_t)b * 128 + y) * 128 + px0 + wv * 16 + q * 4;
#pragma unroll
  for (int n = 0; n < 6; n++) {
    int oc = n * 16 + r;
    float bv = bias[oc];
#pragma unroll
    for (int g = 0; g < 4; g++)
      out[(rowbase + g) * 96 + oc] = f2bf(acc[n][g] + bv);
  }
}

// ---------------- instance-norm stats ----------------
__global__ __launch_bounds__(256) void k_stats(const float* __restrict__ h, float* __restrict__ stats) {
  int bc = blockIdx.x;
  const float* p = h + (size_t)bc * LSEQ;
  float s = 0.f, ss = 0.f;
  for (int i = threadIdx.x; i < LSEQ; i += 256) { float v = p[i]; s += v; ss = fmaf(v, v, ss); }
  __shared__ float rs[256], rss[256];
  int tid = threadIdx.x;
  rs[tid] = s; rss[tid] = ss; __syncthreads();
  for (int o = 128; o > 0; o >>= 1) {
    if (tid < o) { rs[tid] += rs[tid + o]; rss[tid] += rss[tid + o]; }
    __syncthreads();
  }
  if (tid == 0) {
    float m = rs[0] * (1.0f / LSEQ);
    float var = rss[0] * (1.0f / LSEQ) - m * m;
    stats[bc * 2] = m;
    stats[bc * 2 + 1] = rsqrtf(fmaxf(var, 0.f) + 1e-5f);
  }
}

// ---------------- normalize + SELU ----------------
__global__ __launch_bounds__(256) void k_normselu2(const float* __restrict__ h,
    const float* __restrict__ stats, float* __restrict__ Lx, unsigned short* __restrict__ LxR) {
  __shared__ float tile[96 * 65];
  int px0 = blockIdx.x * 64, b = blockIdx.y;
  int tid = threadIdx.x;
  const float kS = 1.0507009873554805f, kA = 1.6732632423543772f;
  for (int t = tid; t < 1536; t += 256) {
    int c = t >> 4, p4 = t & 15;
    size_t ga = ((size_t)b * 96 + c) * LSEQ + px0 + p4 * 4;
    float4 v = *(const float4*)&h[ga];
    float m = stats[(b * 96 + c) * 2], rv = stats[(b * 96 + c) * 2 + 1];
    v.x = (v.x - m) * rv; v.y = (v.y - m) * rv; v.z = (v.z - m) * rv; v.w = (v.w - m) * rv;
    v.x = v.x > 0.f ? kS * v.x : kS * kA * expm1f(v.x);
    v.y = v.y > 0.f ? kS * v.y : kS * kA * expm1f(v.y);
    v.z = v.z > 0.f ? kS * v.z : kS * kA * expm1f(v.z);
    v.w = v.w > 0.f ? kS * v.w : kS * kA * expm1f(v.w);
    *(float4*)&Lx[ga] = v;
    tile[c * 65 + p4 * 4 + 0] = v.x;
    tile[c * 65 + p4 * 4 + 1] = v.y;
    tile[c * 65 + p4 * 4 + 2] = v.z;
    tile[c * 65 + p4 * 4 + 3] = v.w;
  }
  __syncthreads();
  for (int t = tid; t < 768; t += 256) {
    int px = t / 12, c8 = t - px * 12;
    u16x8 o;
#pragma unroll
    for (int jj = 0; jj < 8; jj++) o[jj] = f2bf(tile[(c8 * 8 + jj) * 65 + px]);
    *(u16x8*)&LxR[((size_t)b * LSEQ + px0 + px) * 96 + c8 * 8] = o;
  }
}

// ---------------- causal depthwise conv1d + SiLU ----------------
__global__ __launch_bounds__(256) void k_conv1d(const float* __restrict__ xzx,
    const float* __restrict__ w1d, const float* __restrict__ b1d,
    float* __restrict__ u, unsigned short* __restrict__ uR) {
  int gid = blockIdx.x * 256 + threadIdx.x;
  if (gid >= 2 * LSEQ * DIN) return;
  int d = gid % DIN, bl = gid / DIN;
  int l = bl & (LSEQ - 1);
  float4 w = *(const float4*)&w1d[d * 4];
  float wv[4] = {w.x, w.y, w.z, w.w};
  float acc = b1d[d];
#pragma unroll
  for (int k = 0; k < 4; k++) {
    int lk = l - 3 + k;
    if (lk >= 0) acc = fmaf(wv[k], xzx[(size_t)(bl - 3 + k) * DIN + d], acc);
  }
  float s = siluf(acc);
  u[gid] = s;
  uR[gid] = f2bf(s);
}

// ---------------- scan phase A: per-chunk (prod a, h_end), dt fused ----------------
__global__ __launch_bounds__(192) void k_scanA(const float* __restrict__ u,
    const float* __restrict__ xdbl, const float* __restrict__ Wdt,
    const float* __restrict__ bdt, const float* __restrict__ Alog,
    float* __restrict__ chA, float* __restrict__ chB) {
  int b = blockIdx.y, g = blockIdx.x, d = threadIdx.x;
  __shared__ float Bs[TCH * 16], Dts[TCH * 8];
  for (int i = d; i < TCH * 16; i += 192) {
    int t = i >> 4, n = i & 15;
    Bs[i] = xdbl[(size_t)(b * LSEQ + g * TCH + t) * 38 + 6 + n];
  }
  for (int i = d; i < TCH * 6; i += 192) {
    int t = i / 6, c = i - t * 6;
    Dts[t * 8 + c] = xdbl[(size_t)(b * LSEQ + g * TCH + t) * 38 + c];
  }
  float ac[16];
#pragma unroll
  for (int n = 0; n < 16; n++) ac[n] = -__expf(Alog[d * 16 + n]);
  float wdt[6];
#pragma unroll
  for (int c = 0; c < 6; c++) wdt[c] = Wdt[d * 6 + c];
  float bd = bdt[d];
  __syncthreads();
  float ap[16], hb[16];
#pragma unroll
  for (int n = 0; n < 16; n++) { ap[n] = 1.f; hb[n] = 0.f; }
  for (int t = 0; t < TCH; t++) {
    size_t base = (size_t)(b * LSEQ + g * TCH + t);
    float uv = u[base * DIN + d];
    float dtraw = bd;
#pragma unroll
    for (int c = 0; c < 6; c++) dtraw = fmaf(Dts[t * 8 + c], wdt[c], dtraw);
    float dtv = dtraw > 20.f ? dtraw : log1pf(__expf(dtraw));
    float du = dtv * uv;
    float bs[16];
    const float4* src = (const float4*)&Bs[t * 16];
#pragma unroll
    for (int qq = 0; qq < 4; qq++) {
      float4 v = src[qq];
      bs[qq * 4] = v.x; bs[qq * 4 + 1] = v.y; bs[qq * 4 + 2] = v.z; bs[qq * 4 + 3] = v.w;
    }
#pragma unroll
    for (int n = 0; n < 16; n++) {
      float e = __expf(dtv * ac[n]);
      ap[n] *= e;
      hb[n] = fmaf(hb[n], e, du * bs[n]);
    }
  }
  size_t co = ((size_t)(b * GCH + g) * DIN + d) * 16;
#pragma unroll
  for (int qq = 0; qq < 4; qq++) {
    ((float4*)(chA + co))[qq] = make_float4(ap[qq * 4], ap[qq * 4 + 1], ap[qq * 4 + 2], ap[qq * 4 + 3]);
    ((float4*)(chB + co))[qq] = make_float4(hb[qq * 4], hb[qq * 4 + 1], hb[qq * 4 + 2], hb[qq * 4 + 3]);
  }
}

// ---------------- scan phase B: block-parallel cross-chunk scan ----------------
// R7: was 6144 threads x 512 serial dependent iters (72us, occ 0.9%).
// Now: block per (b,d) [384 blocks x 256 thr]; thread (seg,n) composes 32
// register-cached chunks, 16-step LDS scan over seg aggregates per n, replay.
// compose(first(a1,b1), then(a2,b2)) = (a1*a2, a2*b1 + b2); h_g = b-part (h0=0).
__global__ __launch_bounds__(256) void k_scanB(const float* __restrict__ chA,
    const float* __restrict__ chB, float* __restrict__ h0) {
  __shared__ float sa[16 * 17], sb[16 * 17];
  int blk = blockIdx.x;
  int b = blk / DIN, d = blk - b * DIN;
  int tid = threadIdx.x;
  int seg = tid >> 4, n = tid & 15;
  float ca[32], cb[32];
  float aagg = 1.f, bagg = 0.f;
#pragma unroll 8
  for (int j = 0; j < 32; j++) {
    int g = seg * 32 + j;
    size_t off = ((size_t)(b * GCH + g) * DIN + d) * 16 + n;
    float a = chA[off], bb = chB[off];
    ca[j] = a; cb[j] = bb;
    bagg = fmaf(a, bagg, bb);
    aagg *= a;
  }
  sa[n * 17 + seg] = aagg;
  sb[n * 17 + seg] = bagg;
  __syncthreads();
  if (tid < 16) {
    float pa = 1.f, pb = 0.f;
#pragma unroll
    for (int s = 0; s < 16; s++) {
      float ta = sa[tid * 17 + s], tb = sb[tid * 17 + s];
      sa[tid * 17 + s] = pa;
      sb[tid * 17 + s] = pb;
      pb = fmaf(ta, pb, tb);
      pa *= ta;
    }
  }
  __syncthreads();
  float h = sb[n * 17 + seg];   // exclusive prefix b-part = h at segment start
#pragma unroll 8
  for (int j = 0; j < 32; j++) {
    int g = seg * 32 + j;
    size_t off = ((size_t)(b * GCH + g) * DIN + d) * 16 + n;
    h0[off] = h;
    h = fmaf(ca[j], h, cb[j]);
  }
}

// ---------------- scan phase C: replay + gate, dt fused ----------------
__global__ __launch_bounds__(192) void k_scanC(const float* __restrict__ u,
    const float* __restrict__ xdbl, const float* __restrict__ Wdt,
    const float* __restrict__ bdt, const unsigned short* __restrict__ zR,
    const float* __restrict__ Alog, const float* __restrict__ Dp,
    const float* __restrict__ h0, unsigned short* __restrict__ yR) {
  int b = blockIdx.y, g = blockIdx.x, d = threadIdx.x;
  __shared__ float Bs[TCH * 16], Cs[TCH * 16], Dts[TCH * 8];
  for (int i = d; i < TCH * 16; i += 192) {
    int t = i >> 4, n = i & 15;
    size_t rb = (size_t)(b * LSEQ + g * TCH + t) * 38;
    Bs[i] = xdbl[rb + 6 + n];
    Cs[i] = xdbl[rb + 22 + n];
  }
  for (int i = d; i < TCH * 6; i += 192) {
    int t = i / 6, c = i - t * 6;
    Dts[t * 8 + c] = xdbl[(size_t)(b * LSEQ + g * TCH + t) * 38 + c];
  }
  float ac[16];
#pragma unroll
  for (int n = 0; n < 16; n++) ac[n] = -__expf(Alog[d * 16 + n]);
  float wdt[6];
#pragma unroll
  for (int c = 0; c < 6; c++) wdt[c] = Wdt[d * 6 + c];
  float bd = bdt[d];
  float Dd = Dp[d];
  __syncthreads();
  size_t co = ((size_t)(b * GCH + g) * DIN + d) * 16;
  float h[16];
#pragma unroll
  for (int qq = 0; qq < 4; qq++) {
    float4 v = ((const float4*)(h0 + co))[qq];
    h[qq * 4] = v.x; h[qq * 4 + 1] = v.y; h[qq * 4 + 2] = v.z; h[qq * 4 + 3] = v.w;
  }
  for (int t = 0; t < TCH; t++) {
    size_t base = (size_t)(b * LSEQ + g * TCH + t);
    float uv = u[base * DIN + d];
    float zv = bf2f(zR[base * DIN + d]);
    float dtraw = bd;
#pragma unroll
    for (int c = 0; c < 6; c++) dtraw = fmaf(Dts[t * 8 + c], wdt[c], dtraw);
    float dtv = dtraw > 20.f ? dtraw : log1pf(__expf(dtraw));
    float du = dtv * uv;
    float bs[16], cs[16];
    const float4* sb = (const float4*)&Bs[t * 16];
    const float4* sc = (const float4*)&Cs[t * 16];
#pragma unroll
    for (int qq = 0; qq < 4; qq++) {
      float4 vb = sb[qq], vc = sc[qq];
      bs[qq * 4] = vb.x; bs[qq * 4 + 1] = vb.y; bs[qq * 4 + 2] = vb.z; bs[qq * 4 + 3] = vb.w;
      cs[qq * 4] = vc.x; cs[qq * 4 + 1] = vc.y; cs[qq * 4 + 2] = vc.z; cs[qq * 4 + 3] = vc.w;
    }
    float y0 = 0.f, y1 = 0.f, y2 = 0.f, y3 = 0.f;
#pragma unroll
    for (int n = 0; n < 16; n++) {
      float e = __expf(dtv * ac[n]);
      h[n] = fmaf(h[n], e, du * bs[n]);
      float p = h[n] * cs[n];
      if ((n & 3) == 0) y0 += p; else if ((n & 3) == 1) y1 += p;
      else if ((n & 3) == 2) y2 += p; else y3 += p;
    }
    float yv = ((y0 + y1) + (y2 + y3)) + uv * Dd;
    yR[base * DIN + d] = f2bf(yv * siluf(zv));
  }
}

// ---------------- launch ----------------
extern "C" void kernel_launch(void* const* d_in, const int* in_sizes, int n_in,
                              void* d_out, int out_size, void* d_ws, size_t ws_size,
                              hipStream_t stream) {
  (void)in_sizes; (void)n_in; (void)out_size; (void)ws_size;
  const float* x    = (const float*)d_in[0];
  const float* Hx   = (const float*)d_in[1];
  const float* c1w  = (const float*)d_in[2];
  const float* c1b  = (const float*)d_in[3];
  const float* c2w  = (const float*)d_in[4];
  const float* c2b  = (const float*)d_in[5];
  const float* c3w  = (const float*)d_in[6];
  const float* c3b  = (const float*)d_in[7];
  const float* Win  = (const float*)d_in[8];
  const float* w1d  = (const float*)d_in[9];
  const float* b1d  = (const float*)d_in[10];
  const float* Wx   = (const float*)d_in[11];
  const float* Wdt  = (const float*)d_in[12];
  const float* bdt  = (const float*)d_in[13];
  const float* Alog = (const float*)d_in[14];
  const float* Dp   = (const float*)d_in[15];
  const float* Wout = (const float*)d_in[16];
  float* out = (float*)d_out;

  float* ws = (float*)d_ws;
  const size_t F = (size_t)2 * 96 * LSEQ;      // 3,145,728 floats
  const size_t Fh = F / 2;

  // layout (floats), total 9F + 92,544 ~= 108.6 MB (see R6 comments)
  float*          b_up = ws;
  float*          b_h3 = ws;
  float*          chA  = ws;
  float*          b_Lx = ws + F;
  unsigned short* R1   = (unsigned short*)(ws + 2 * F);
  unsigned short* R2   = (unsigned short*)(ws + 2 * F + Fh);
  float*          xdbl = ws + 2 * F + Fh;
  float*          xzx  = ws + 3 * F;
  float*          chB  = ws + 3 * F;
  float*          h0b  = ws + 4 * F;
  unsigned short* zRb  = (unsigned short*)(ws + 5 * F);
  unsigned short* R3   = (unsigned short*)(ws + 6 * F);
  float*          b_u  = ws + 7 * F;
  unsigned short* Wp   = (unsigned short*)(ws + 9 * F);
  float*          b_st = ws + 9 * F + 92160;

  k_packw<<<dim3(720), dim3(256), 0, stream>>>(c1w, c2w, c3w, Win, Wx, Wout, Wp);
  k_upsample<<<dim3(12288), dim3(256), 0, stream>>>(x, b_up);
  k_gemm<SRC_PLANAR2, OUT_BF16R, 6><<<dim3(256, 1), dim3(256), 0, stream>>>(
      b_up, Hx, 96, Wp, c1b, R1, nullptr, nullptr, 288, 0, 0);
  k_conv3x3m<<<dim3(512), dim3(256), 0, stream>>>(R1, Wp + 27648, c2b, R2);
  k_gemm<SRC_ROWS, OUT_F32P, 6><<<dim3(256, 1), dim3(256), 0, stream>>>(
      R2, nullptr, 0, Wp + 110592, c3b, b_h3, nullptr, nullptr, 96, 0, 0);
  k_stats<<<dim3(192), dim3(256), 0, stream>>>(b_h3, b_st);
  k_normselu2<<<dim3(256, 2), dim3(256), 0, stream>>>(b_h3, b_st, b_Lx, R1);
  k_gemm<SRC_ROWS, OUT_XZ, 6><<<dim3(256, 4), dim3(256), 0, stream>>>(
      R1, nullptr, 0, Wp + 119808, nullptr, xzx, zRb, nullptr, 96, 192, 0);
  k_conv1d<<<dim3((2 * LSEQ * DIN + 255) / 256), dim3(256), 0, stream>>>(xzx, w1d, b1d, b_u, R3);
  k_gemm<SRC_ROWS, OUT_F32R, 3><<<dim3(256, 1), dim3(256), 0, stream>>>(
      R3, nullptr, 0, Wp + 156672, nullptr, xdbl, nullptr, nullptr, 192, 38, 38);
  k_scanA<<<dim3(GCH, 2), dim3(192), 0, stream>>>(b_u, xdbl, Wdt, bdt, Alog, chA, chB);
  k_scanB<<<dim3(2 * DIN), dim3(256), 0, stream>>>(chA, chB, h0b);
  k_scanC<<<dim3(GCH, 2), dim3(192), 0, stream>>>(b_u, xdbl, Wdt, bdt, zRb, Alog, Dp, h0b, R3);
  k_gemm<SRC_ROWS, OUT_F32P_RES, 6><<<dim3(256, 1), dim3(256), 0, stream>>>(
      R3, nullptr, 0, Wp + 165888, nullptr, out, nullptr, b_Lx, 192, 0, 0);
}

// Round 8
// 348.672 us; speedup vs baseline: 1.2216x; 1.0916x over previous
//
#include <hip/hip_runtime.h>
#include <hip/hip_bf16.h>
#include <math.h>

#define LSEQ 16384
#define DIN  192
#define GCH  512
#define TCH  32

typedef float f4v __attribute__((ext_vector_type(4)));
typedef short s8v __attribute__((ext_vector_type(8)));
typedef unsigned short u16x8 __attribute__((ext_vector_type(8)));

__device__ __forceinline__ float siluf(float x) { return __fdividef(x, 1.0f + __expf(-x)); }
__device__ __forceinline__ float fexp2(float x) {
#if __has_builtin(__builtin_amdgcn_exp2f)
  return __builtin_amdgcn_exp2f(x);
#else
  return __expf(x * 0.69314718056f);
#endif
}
__device__ __forceinline__ unsigned short f2bf(float f) {
  unsigned int u = __float_as_uint(f);
  unsigned int r = (u + 0x7FFFu + ((u >> 16) & 1u)) >> 16;
  return (unsigned short)r;
}
__device__ __forceinline__ float bf2f(unsigned short s) {
  return __uint_as_float(((unsigned int)s) << 16);
}

// ---------------- weight pre-pack to bf16 ----------------
__global__ __launch_bounds__(256) void k_packw(const float* __restrict__ c1w,
    const float* __restrict__ c2w, const float* __restrict__ c3w,
    const float* __restrict__ Win, const float* __restrict__ Wx,
    const float* __restrict__ Wout, unsigned short* __restrict__ P) {
  int i = blockIdx.x * 256 + threadIdx.x;
  if (i >= 184320) return;
  if (i < 27648) { P[i] = f2bf(c1w[i]); return; }
  int j = i - 27648;
  if (j < 82944) {
    int cc = j / 27648, r = j - cc * 27648;
    int kk = r / 3072, r2 = r - kk * 3072;
    int oc = r2 >> 5, icl = r2 & 31;
    int ky = kk / 3, kx = kk - ky * 3;
    P[i] = f2bf(c2w[((oc * 96 + cc * 32 + icl) * 3 + ky) * 3 + kx]);
    return;
  }
  j -= 82944;
  if (j < 9216) { P[i] = f2bf(c3w[j]); return; }
  j -= 9216;
  if (j < 36864) { P[i] = f2bf(Win[j]); return; }
  j -= 36864;
  if (j < 9216) {
    int oc = j / 192, k = j - oc * 192;
    P[i] = (oc < 38) ? f2bf(Wx[oc * 192 + k]) : (unsigned short)0;
    return;
  }
  j -= 9216;
  P[i] = f2bf(Wout[j]);
}

// ---------------- generic MFMA GEMM ----------------
#define SRC_PLANAR2 0
#define SRC_ROWS    1
#define SRC_UPCAT   2   // xa = x [2,96,64,64] (bilinear 2x inline), xb = Hx [2,192,128,128]
#define OUT_BF16R    0
#define OUT_F32P     1
#define OUT_F32R     2
#define OUT_F32P_RES 4
#define OUT_XZ       5

template<int SM, int OM, int NT>
__global__ __launch_bounds__(256) void k_gemm(
    const void* __restrict__ xa, const void* __restrict__ xb, int CA,
    const unsigned short* __restrict__ Wp, const float* __restrict__ bias,
    void* __restrict__ outv, void* __restrict__ outv2, const float* __restrict__ resid,
    int K, int ostride, int ng) {
  __shared__ unsigned short x_t[128 * 96];
  __shared__ unsigned short w_t[NT * 16 * 96];
  Wp += (size_t)blockIdx.y * 96 * K;
  int pxg0 = blockIdx.x * 128;
  int b = pxg0 >> 14, px_in0 = pxg0 & 16383;
  int tid = threadIdx.x, lane = tid & 63, wv = tid >> 6;
  int r = lane & 15, q = lane >> 4;
  f4v acc[2][NT];
#pragma unroll
  for (int mi = 0; mi < 2; mi++)
#pragma unroll
    for (int n = 0; n < NT; n++) acc[mi][n] = (f4v)0.0f;
  int nchunk = K / 96;
  for (int kc = 0; kc < nchunk; kc++) {
    for (int t = tid; t < NT * 16 * 12; t += 256) {
      int row = t / 12, u8 = t - row * 12;
      *(u16x8*)&w_t[row * 96 + u8 * 8] = *(const u16x8*)&Wp[(size_t)row * K + kc * 96 + u8 * 8];
    }
    if (SM == SRC_PLANAR2) {
      const float* A0 = (const float*)xa;
      const float* A1 = (const float*)xb;
      int CB = K - CA;
      for (int t = tid; t < 3072; t += 256) {
        int px4 = t / 96, c_l = t - px4 * 96;
        int c = kc * 96 + c_l;
        const float* sp = (c < CA) ? (A0 + ((size_t)b * CA + c) * LSEQ + px_in0 + px4 * 4)
                                   : (A1 + ((size_t)b * CB + (c - CA)) * LSEQ + px_in0 + px4 * 4);
        float4 v = *(const float4*)sp;
        x_t[(px4 * 4 + 0) * 96 + c_l] = f2bf(v.x);
        x_t[(px4 * 4 + 1) * 96 + c_l] = f2bf(v.y);
        x_t[(px4 * 4 + 2) * 96 + c_l] = f2bf(v.z);
        x_t[(px4 * 4 + 3) * 96 + c_l] = f2bf(v.w);
      }
    } else if (SM == SRC_UPCAT) {
      const float* X0 = (const float*)xa;   // [2,96,64,64]
      const float* HX = (const float*)xb;   // [2,192,128,128]
      for (int t = tid; t < 3072; t += 256) {
        int px4 = t / 96, c_l = t - px4 * 96;
        int c = kc * 96 + c_l;
        int pxl = px4 * 4;
        if (c < 96) {
          int pxg = px_in0 + pxl;
          int oh = pxg >> 7, ow0 = pxg & 127;
          float pr = oh * (63.0f / 127.0f);
          int r0 = (int)pr; float rw = pr - (float)r0; int r1 = min(r0 + 1, 63);
          const float* rp0 = X0 + ((size_t)b * 96 + c) * 4096 + r0 * 64;
          const float* rp1 = X0 + ((size_t)b * 96 + c) * 4096 + r1 * 64;
#pragma unroll
          for (int g = 0; g < 4; g++) {
            int ow = ow0 + g;
            float pc = ow * (63.0f / 127.0f);
            int c0 = (int)pc; float cw = pc - (float)c0; int c1 = min(c0 + 1, 63);
            float v00 = rp0[c0], v01 = rp0[c1], v10 = rp1[c0], v11 = rp1[c1];
            float top = v00 + (v10 - v00) * rw;
            float bot = v01 + (v11 - v01) * rw;
            x_t[(pxl + g) * 96 + c_l] = f2bf(top + (bot - top) * cw);
          }
        } else {
          float4 v = *(const float4*)&HX[((size_t)b * 192 + (c - 96)) * LSEQ + px_in0 + pxl];
          x_t[(pxl + 0) * 96 + c_l] = f2bf(v.x);
          x_t[(pxl + 1) * 96 + c_l] = f2bf(v.y);
          x_t[(pxl + 2) * 96 + c_l] = f2bf(v.z);
          x_t[(pxl + 3) * 96 + c_l] = f2bf(v.w);
        }
      }
    } else {
      const unsigned short* X = (const unsigned short*)xa;
      for (int t = tid; t < 1536; t += 256) {
        int rr = t / 12, u8 = t - rr * 12;
        *(u16x8*)&x_t[rr * 96 + u8 * 8] =
            *(const u16x8*)&X[(size_t)(pxg0 + rr) * K + kc * 96 + u8 * 8];
      }
    }
    __syncthreads();
#pragma unroll
    for (int k0 = 0; k0 < 96; k0 += 32) {
      s8v a0 = *(const s8v*)&x_t[((wv * 2 + 0) * 16 + r) * 96 + k0 + q * 8];
      s8v a1 = *(const s8v*)&x_t[((wv * 2 + 1) * 16 + r) * 96 + k0 + q * 8];
#pragma unroll
      for (int n = 0; n < NT; n++) {
        s8v bb = *(const s8v*)&w_t[(n * 16 + r) * 96 + k0 + q * 8];
        acc[0][n] = __builtin_amdgcn_mfma_f32_16x16x32_bf16(a0, bb, acc[0][n], 0, 0, 0);
        acc[1][n] = __builtin_amdgcn_mfma_f32_16x16x32_bf16(a1, bb, acc[1][n], 0, 0, 0);
      }
    }
    __syncthreads();
  }
#pragma unroll
  for (int mi = 0; mi < 2; mi++) {
    int pxl = (wv * 2 + mi) * 16 + q * 4;
    int pxg = pxg0 + pxl;
#pragma unroll
    for (int n = 0; n < NT; n++) {
      int oc = n * 16 + r;
      if (OM == OUT_BF16R) {
        float bv = bias[oc];
        unsigned short* O = (unsigned short*)outv;
#pragma unroll
        for (int g = 0; g < 4; g++)
          O[(size_t)(pxg + g) * 96 + oc] = f2bf(acc[mi][n][g] + bv);
      } else if (OM == OUT_F32P) {
        float bv = bias[oc];
        float* O = (float*)outv;
        float4 o = make_float4(acc[mi][n][0] + bv, acc[mi][n][1] + bv,
                               acc[mi][n][2] + bv, acc[mi][n][3] + bv);
        *(float4*)&O[((size_t)b * 96 + oc) * LSEQ + px_in0 + pxl] = o;
      } else if (OM == OUT_F32P_RES) {
        float* O = (float*)outv;
        size_t ad = ((size_t)b * 96 + oc) * LSEQ + px_in0 + pxl;
        float4 rv = *(const float4*)&resid[ad];
        float4 o = make_float4(acc[mi][n][0] + rv.x, acc[mi][n][1] + rv.y,
                               acc[mi][n][2] + rv.z, acc[mi][n][3] + rv.w);
        *(float4*)&O[ad] = o;
      } else if (OM == OUT_F32R) {
        float* O = (float*)outv;
        int ocg = blockIdx.y * 96 + oc;
        if (ocg < ng) {
#pragma unroll
          for (int g = 0; g < 4; g++)
            O[(size_t)(pxg + g) * ostride + ocg] = acc[mi][n][g];
        }
      } else { // OUT_XZ
        int ocg = (blockIdx.y & 1) * 96 + oc;
        if (blockIdx.y < 2) {
          float* O = (float*)outv;
#pragma unroll
          for (int g = 0; g < 4; g++)
            O[(size_t)(pxg + g) * 192 + ocg] = acc[mi][n][g];
        } else {
          unsigned short* O = (unsigned short*)outv2;
#pragma unroll
          for (int g = 0; g < 4; g++)
            O[(size_t)(pxg + g) * 192 + ocg] = f2bf(acc[mi][n][g]);
        }
      }
    }
  }
}

// ---------------- conv3x3 implicit-GEMM MFMA ----------------
__global__ __launch_bounds__(256) void k_conv3x3m(const unsigned short* __restrict__ X,
    const unsigned short* __restrict__ Wp2, const float* __restrict__ bias,
    unsigned short* __restrict__ out) {
  __shared__ unsigned short in_t[3 * 68 * 32];
  __shared__ unsigned short w_t[9 * 96 * 32];
  int bi = blockIdx.x;
  int hx = bi & 1, y = (bi >> 1) & 127, b = bi >> 8;
  int px0 = hx * 64;
  int tid = threadIdx.x, lane = tid & 63, wv = tid >> 6;
  int r = lane & 15, q = lane >> 4;
  f4v acc[6];
#pragma unroll
  for (int n = 0; n < 6; n++) acc[n] = (f4v)0.0f;
  for (int cc = 0; cc < 3; cc++) {
    for (int t = tid; t < 3456; t += 256)
      *(u16x8*)&w_t[t * 8] = *(const u16x8*)&Wp2[cc * 27648 + t * 8];
    for (int t = tid; t < 792; t += 256) {
      int row = t / 264, rem = t - row * 264;
      int c_l = rem >> 2, icq = rem & 3;
      int gy = y - 1 + row, gx = px0 - 1 + c_l;
      u16x8 v = {0, 0, 0, 0, 0, 0, 0, 0};
      if (gy >= 0 && gy < 128 && gx >= 0 && gx < 128)
        v = *(const u16x8*)&X[(((size_t)b * 128 + gy) * 128 + gx) * 96 + cc * 32 + icq * 8];
      *(u16x8*)&in_t[(row * 68 + c_l) * 32 + icq * 8] = v;
    }
    __syncthreads();
#pragma unroll
    for (int kk = 0; kk < 9; kk++) {
      int ky = kk / 3, kx = kk - ky * 3;
      s8v a = *(const s8v*)&in_t[(ky * 68 + wv * 16 + r + kx) * 32 + q * 8];
#pragma unroll
      for (int n = 0; n < 6; n++) {
        s8v bb = *(const s8v*)&w_t[(kk * 96 + n * 16 + r) * 32 + q * 8];
        acc[n] = __builtin_amdgcn_mfma_f32_16x16x32_bf16(a, bb, acc[n], 0, 0, 0);
      }
    }
    __syncthreads();
  }
  size_t rowbase = ((size_t)b * 128 + y) * 128 + px0 + wv * 16 + q * 4;
#pragma unroll
  for (int n = 0; n < 6; n++) {
    int oc = n * 16 + r;
    float bv = bias[oc];
#pragma unroll
    for (int g = 0; g < 4; g++)
      out[(rowbase + g) * 96 + oc] = f2bf(acc[n][g] + bv);
  }
}

// ---------------- instance-norm stats ----------------
__global__ __launch_bounds__(256) void k_stats(const float* __restrict__ h, float* __restrict__ stats) {
  int bc = blockIdx.x;
  const float* p = h + (size_t)bc * LSEQ;
  float s = 0.f, ss = 0.f;
  for (int i = threadIdx.x; i < LSEQ; i += 256) { float v = p[i]; s += v; ss = fmaf(v, v, ss); }
  __shared__ float rs[256], rss[256];
  int tid = threadIdx.x;
  rs[tid] = s; rss[tid] = ss; __syncthreads();
  for (int o = 128; o > 0; o >>= 1) {
    if (tid < o) { rs[tid] += rs[tid + o]; rss[tid] += rss[tid + o]; }
    __syncthreads();
  }
  if (tid == 0) {
    float m = rs[0] * (1.0f / LSEQ);
    float var = rss[0] * (1.0f / LSEQ) - m * m;
    stats[bc * 2] = m;
    stats[bc * 2 + 1] = rsqrtf(fmaxf(var, 0.f) + 1e-5f);
  }
}

// ---------------- normalize + SELU ----------------
__device__ __forceinline__ float seluf(float v) {
  const float kS = 1.0507009873554805f, kSA = 1.0507009873554805f * 1.6732632423543772f;
  return v > 0.f ? kS * v : kSA * (__expf(v) - 1.f);
}
__global__ __launch_bounds__(256) void k_normselu2(const float* __restrict__ h,
    const float* __restrict__ stats, float* __restrict__ Lx, unsigned short* __restrict__ LxR) {
  __shared__ float tile[96 * 65];
  int px0 = blockIdx.x * 64, b = blockIdx.y;
  int tid = threadIdx.x;
  for (int t = tid; t < 1536; t += 256) {
    int c = t >> 4, p4 = t & 15;
    size_t ga = ((size_t)b * 96 + c) * LSEQ + px0 + p4 * 4;
    float4 v = *(const float4*)&h[ga];
    float m = stats[(b * 96 + c) * 2], rv = stats[(b * 96 + c) * 2 + 1];
    v.x = seluf((v.x - m) * rv);
    v.y = seluf((v.y - m) * rv);
    v.z = seluf((v.z - m) * rv);
    v.w = seluf((v.w - m) * rv);
    *(float4*)&Lx[ga] = v;
    tile[c * 65 + p4 * 4 + 0] = v.x;
    tile[c * 65 + p4 * 4 + 1] = v.y;
    tile[c * 65 + p4 * 4 + 2] = v.z;
    tile[c * 65 + p4 * 4 + 3] = v.w;
  }
  __syncthreads();
  for (int t = tid; t < 768; t += 256) {
    int px = t / 12, c8 = t - px * 12;
    u16x8 o;
#pragma unroll
    for (int jj = 0; jj < 8; jj++) o[jj] = f2bf(tile[(c8 * 8 + jj) * 65 + px]);
    *(u16x8*)&LxR[((size_t)b * LSEQ + px0 + px) * 96 + c8 * 8] = o;
  }
}

// ---------------- causal depthwise conv1d + SiLU ----------------
__global__ __launch_bounds__(256) void k_conv1d(const float* __restrict__ xzx,
    const float* __restrict__ w1d, const float* __restrict__ b1d,
    float* __restrict__ u, unsigned short* __restrict__ uR) {
  int gid = blockIdx.x * 256 + threadIdx.x;
  if (gid >= 2 * LSEQ * DIN) return;
  int d = gid % DIN, bl = gid / DIN;
  int l = bl & (LSEQ - 1);
  float4 w = *(const float4*)&w1d[d * 4];
  float wv[4] = {w.x, w.y, w.z, w.w};
  float acc = b1d[d];
#pragma unroll
  for (int k = 0; k < 4; k++) {
    int lk = l - 3 + k;
    if (lk >= 0) acc = fmaf(wv[k], xzx[(size_t)(bl - 3 + k) * DIN + d], acc);
  }
  float s = siluf(acc);
  u[gid] = s;
  uR[gid] = f2bf(s);
}

// ---------------- scan phase A: per-chunk (prod a, h_end), dt fused ----------------
// R8: register-staged u, dtv precomputed (pipelined trans), native softplus, exp2 decay.
__global__ __launch_bounds__(192, 3) void k_scanA(const float* __restrict__ u,
    const float* __restrict__ xdbl, const float* __restrict__ Wdt,
    const float* __restrict__ bdt, const float* __restrict__ Alog,
    float* __restrict__ chA, float* __restrict__ chB) {
  int b = blockIdx.y, g = blockIdx.x, d = threadIdx.x;
  __shared__ float Bs[TCH * 16], Dts[TCH * 8];
  for (int i = d; i < TCH * 16; i += 192) {
    int t = i >> 4, n = i & 15;
    Bs[i] = xdbl[(size_t)(b * LSEQ + g * TCH + t) * 38 + 6 + n];
  }
  for (int i = d; i < TCH * 6; i += 192) {
    int t = i / 6, c = i - t * 6;
    Dts[t * 8 + c] = xdbl[(size_t)(b * LSEQ + g * TCH + t) * 38 + c];
  }
  float ac2[16];
#pragma unroll
  for (int n = 0; n < 16; n++) ac2[n] = -__expf(Alog[d * 16 + n]) * 1.44269504f;
  float wdt[6];
#pragma unroll
  for (int c = 0; c < 6; c++) wdt[c] = Wdt[d * 6 + c];
  float bd = bdt[d];
  size_t base0 = (size_t)(b * LSEQ + g * TCH);
  float uu[TCH];
#pragma unroll
  for (int t = 0; t < TCH; t++) uu[t] = u[(base0 + t) * DIN + d];
  __syncthreads();
  float dtv[TCH];
#pragma unroll
  for (int t = 0; t < TCH; t++) {
    float dr = bd;
#pragma unroll
    for (int c = 0; c < 6; c++) dr = fmaf(Dts[t * 8 + c], wdt[c], dr);
    dtv[t] = dr > 20.f ? dr : __logf(1.f + __expf(dr));
  }
  float ap[16], hb[16];
#pragma unroll
  for (int n = 0; n < 16; n++) { ap[n] = 1.f; hb[n] = 0.f; }
  for (int t = 0; t < TCH; t++) {
    float dl2 = dtv[t] * 1.f;
    float du = dtv[t] * uu[t];
    float bs[16];
    const float4* src = (const float4*)&Bs[t * 16];
#pragma unroll
    for (int qq = 0; qq < 4; qq++) {
      float4 v = src[qq];
      bs[qq * 4] = v.x; bs[qq * 4 + 1] = v.y; bs[qq * 4 + 2] = v.z; bs[qq * 4 + 3] = v.w;
    }
#pragma unroll
    for (int n = 0; n < 16; n++) {
      float e = fexp2(dl2 * ac2[n]);
      ap[n] *= e;
      hb[n] = fmaf(hb[n], e, du * bs[n]);
    }
  }
  size_t co = ((size_t)(b * GCH + g) * DIN + d) * 16;
#pragma unroll
  for (int qq = 0; qq < 4; qq++) {
    ((float4*)(chA + co))[qq] = make_float4(ap[qq * 4], ap[qq * 4 + 1], ap[qq * 4 + 2], ap[qq * 4 + 3]);
    ((float4*)(chB + co))[qq] = make_float4(hb[qq * 4], hb[qq * 4 + 1], hb[qq * 4 + 2], hb[qq * 4 + 3]);
  }
}

// ---------------- scan phase B: block-parallel cross-chunk scan ----------------
__global__ __launch_bounds__(256) void k_scanB(const float* __restrict__ chA,
    const float* __restrict__ chB, float* __restrict__ h0) {
  __shared__ float sa[16 * 17], sb[16 * 17];
  int blk = blockIdx.x;
  int b = blk / DIN, d = blk - b * DIN;
  int tid = threadIdx.x;
  int seg = tid >> 4, n = tid & 15;
  float ca[32], cb[32];
  float aagg = 1.f, bagg = 0.f;
#pragma unroll 8
  for (int j = 0; j < 32; j++) {
    int g = seg * 32 + j;
    size_t off = ((size_t)(b * GCH + g) * DIN + d) * 16 + n;
    float a = chA[off], bb = chB[off];
    ca[j] = a; cb[j] = bb;
    bagg = fmaf(a, bagg, bb);
    aagg *= a;
  }
  sa[n * 17 + seg] = aagg;
  sb[n * 17 + seg] = bagg;
  __syncthreads();
  if (tid < 16) {
    float pa = 1.f, pb = 0.f;
#pragma unroll
    for (int s = 0; s < 16; s++) {
      float ta = sa[tid * 17 + s], tb = sb[tid * 17 + s];
      sa[tid * 17 + s] = pa;
      sb[tid * 17 + s] = pb;
      pb = fmaf(ta, pb, tb);
      pa *= ta;
    }
  }
  __syncthreads();
  float h = sb[n * 17 + seg];
#pragma unroll 8
  for (int j = 0; j < 32; j++) {
    int g = seg * 32 + j;
    size_t off = ((size_t)(b * GCH + g) * DIN + d) * 16 + n;
    h0[off] = h;
    h = fmaf(ca[j], h, cb[j]);
  }
}

// ---------------- scan phase C: replay + gate, dt fused ----------------
__global__ __launch_bounds__(192, 3) void k_scanC(const float* __restrict__ u,
    const float* __restrict__ xdbl, const float* __restrict__ Wdt,
    const float* __restrict__ bdt, const unsigned short* __restrict__ zR,
    const float* __restrict__ Alog, const float* __restrict__ Dp,
    const float* __restrict__ h0, unsigned short* __restrict__ yR) {
  int b = blockIdx.y, g = blockIdx.x, d = threadIdx.x;
  __shared__ float Bs[TCH * 16], Cs[TCH * 16], Dts[TCH * 8];
  for (int i = d; i < TCH * 16; i += 192) {
    int t = i >> 4, n = i & 15;
    size_t rb = (size_t)(b * LSEQ + g * TCH + t) * 38;
    Bs[i] = xdbl[rb + 6 + n];
    Cs[i] = xdbl[rb + 22 + n];
  }
  for (int i = d; i < TCH * 6; i += 192) {
    int t = i / 6, c = i - t * 6;
    Dts[t * 8 + c] = xdbl[(size_t)(b * LSEQ + g * TCH + t) * 38 + c];
  }
  float ac2[16];
#pragma unroll
  for (int n = 0; n < 16; n++) ac2[n] = -__expf(Alog[d * 16 + n]) * 1.44269504f;
  float wdt[6];
#pragma unroll
  for (int c = 0; c < 6; c++) wdt[c] = Wdt[d * 6 + c];
  float bd = bdt[d];
  float Dd = Dp[d];
  size_t base0 = (size_t)(b * LSEQ + g * TCH);
  float uu[TCH];
#pragma unroll
  for (int t = 0; t < TCH; t++) uu[t] = u[(base0 + t) * DIN + d];
  size_t co = ((size_t)(b * GCH + g) * DIN + d) * 16;
  float h[16];
#pragma unroll
  for (int qq = 0; qq < 4; qq++) {
    float4 v = ((const float4*)(h0 + co))[qq];
    h[qq * 4] = v.x; h[qq * 4 + 1] = v.y; h[qq * 4 + 2] = v.z; h[qq * 4 + 3] = v.w;
  }
  __syncthreads();
  float dtv[TCH];
#pragma unroll
  for (int t = 0; t < TCH; t++) {
    float dr = bd;
#pragma unroll
    for (int c = 0; c < 6; c++) dr = fmaf(Dts[t * 8 + c], wdt[c], dr);
    dtv[t] = dr > 20.f ? dr : __logf(1.f + __expf(dr));
  }
  for (int t = 0; t < TCH; t++) {
    float du = dtv[t] * uu[t];
    float zv = bf2f(zR[(base0 + t) * DIN + d]);
    float bs[16], cs[16];
    const float4* sbp = (const float4*)&Bs[t * 16];
    const float4* scp = (const float4*)&Cs[t * 16];
#pragma unroll
    for (int qq = 0; qq < 4; qq++) {
      float4 vb = sbp[qq], vc = scp[qq];
      bs[qq * 4] = vb.x; bs[qq * 4 + 1] = vb.y; bs[qq * 4 + 2] = vb.z; bs[qq * 4 + 3] = vb.w;
      cs[qq * 4] = vc.x; cs[qq * 4 + 1] = vc.y; cs[qq * 4 + 2] = vc.z; cs[qq * 4 + 3] = vc.w;
    }
    float y0 = 0.f, y1 = 0.f, y2 = 0.f, y3 = 0.f;
#pragma unroll
    for (int n = 0; n < 16; n++) {
      float e = fexp2(dtv[t] * ac2[n]);
      h[n] = fmaf(h[n], e, du * bs[n]);
      float p = h[n] * cs[n];
      if ((n & 3) == 0) y0 += p; else if ((n & 3) == 1) y1 += p;
      else if ((n & 3) == 2) y2 += p; else y3 += p;
    }
    float yv = ((y0 + y1) + (y2 + y3)) + uu[t] * Dd;
    yR[(base0 + t) * DIN + d] = f2bf(yv * siluf(zv));
  }
}

// ---------------- launch ----------------
extern "C" void kernel_launch(void* const* d_in, const int* in_sizes, int n_in,
                              void* d_out, int out_size, void* d_ws, size_t ws_size,
                              hipStream_t stream) {
  (void)in_sizes; (void)n_in; (void)out_size; (void)ws_size;
  const float* x    = (const float*)d_in[0];
  const float* Hx   = (const float*)d_in[1];
  const float* c1w  = (const float*)d_in[2];
  const float* c1b  = (const float*)d_in[3];
  const float* c2w  = (const float*)d_in[4];
  const float* c2b  = (const float*)d_in[5];
  const float* c3w  = (const float*)d_in[6];
  const float* c3b  = (const float*)d_in[7];
  const float* Win  = (const float*)d_in[8];
  const float* w1d  = (const float*)d_in[9];
  const float* b1d  = (const float*)d_in[10];
  const float* Wx   = (const float*)d_in[11];
  const float* Wdt  = (const float*)d_in[12];
  const float* bdt  = (const float*)d_in[13];
  const float* Alog = (const float*)d_in[14];
  const float* Dp   = (const float*)d_in[15];
  const float* Wout = (const float*)d_in[16];
  float* out = (float*)d_out;

  float* ws = (float*)d_ws;
  const size_t F = (size_t)2 * 96 * LSEQ;
  const size_t Fh = F / 2;

  // layout (floats), total 9F + 92,544 ~= 108.6 MB (see R6 comments; b_up region
  // now only h3/chA since upsample is fused into conv1 staging)
  float*          b_h3 = ws;
  float*          chA  = ws;
  float*          b_Lx = ws + F;
  unsigned short* R1   = (unsigned short*)(ws + 2 * F);
  unsigned short* R2   = (unsigned short*)(ws + 2 * F + Fh);
  float*          xdbl = ws + 2 * F + Fh;
  float*          xzx  = ws + 3 * F;
  float*          chB  = ws + 3 * F;
  float*          h0b  = ws + 4 * F;
  unsigned short* zRb  = (unsigned short*)(ws + 5 * F);
  unsigned short* R3   = (unsigned short*)(ws + 6 * F);
  float*          b_u  = ws + 7 * F;
  unsigned short* Wp   = (unsigned short*)(ws + 9 * F);
  float*          b_st = ws + 9 * F + 92160;

  k_packw<<<dim3(720), dim3(256), 0, stream>>>(c1w, c2w, c3w, Win, Wx, Wout, Wp);
  // conv1 with fused bilinear upsample of x
  k_gemm<SRC_UPCAT, OUT_BF16R, 6><<<dim3(256, 1), dim3(256), 0, stream>>>(
      x, Hx, 96, Wp, c1b, R1, nullptr, nullptr, 288, 0, 0);
  k_conv3x3m<<<dim3(512), dim3(256), 0, stream>>>(R1, Wp + 27648, c2b, R2);
  k_gemm<SRC_ROWS, OUT_F32P, 6><<<dim3(256, 1), dim3(256), 0, stream>>>(
      R2, nullptr, 0, Wp + 110592, c3b, b_h3, nullptr, nullptr, 96, 0, 0);
  k_stats<<<dim3(192), dim3(256), 0, stream>>>(b_h3, b_st);
  k_normselu2<<<dim3(256, 2), dim3(256), 0, stream>>>(b_h3, b_st, b_Lx, R1);
  k_gemm<SRC_ROWS, OUT_XZ, 6><<<dim3(256, 4), dim3(256), 0, stream>>>(
      R1, nullptr, 0, Wp + 119808, nullptr, xzx, zRb, nullptr, 96, 192, 0);
  k_conv1d<<<dim3((2 * LSEQ * DIN + 255) / 256), dim3(256), 0, stream>>>(xzx, w1d, b1d, b_u, R3);
  k_gemm<SRC_ROWS, OUT_F32R, 3><<<dim3(256, 1), dim3(256), 0, stream>>>(
      R3, nullptr, 0, Wp + 156672, nullptr, xdbl, nullptr, nullptr, 192, 38, 38);
  k_scanA<<<dim3(GCH, 2), dim3(192), 0, stream>>>(b_u, xdbl, Wdt, bdt, Alog, chA, chB);
  k_scanB<<<dim3(2 * DIN), dim3(256), 0, stream>>>(chA, chB, h0b);
  k_scanC<<<dim3(GCH, 2), dim3(192), 0, stream>>>(b_u, xdbl, Wdt, bdt, zRb, Alog, Dp, h0b, R3);
  k_gemm<SRC_ROWS, OUT_F32P_RES, 6><<<dim3(256, 1), dim3(256), 0, stream>>>(
      R3, nullptr, 0, Wp + 165888, nullptr, out, nullptr, b_Lx, 192, 0, 0);
}

// Round 9
// 347.410 us; speedup vs baseline: 1.2260x; 1.0036x over previous
//
#include <hip/hip_runtime.h>
#include <hip/hip_bf16.h>
#include <math.h>

#define LSEQ 16384
#define DIN  192
#define GCH  512
#define TCH  32

typedef float f4v __attribute__((ext_vector_type(4)));
typedef short s8v __attribute__((ext_vector_type(8)));
typedef unsigned short u16x8 __attribute__((ext_vector_type(8)));

__device__ __forceinline__ float siluf(float x) { return __fdividef(x, 1.0f + __expf(-x)); }
__device__ __forceinline__ float fexp2(float x) {
#if __has_builtin(__builtin_amdgcn_exp2f)
  return __builtin_amdgcn_exp2f(x);
#else
  return __expf(x * 0.69314718056f);
#endif
}
__device__ __forceinline__ unsigned short f2bf(float f) {
  unsigned int u = __float_as_uint(f);
  unsigned int r = (u + 0x7FFFu + ((u >> 16) & 1u)) >> 16;
  return (unsigned short)r;
}
__device__ __forceinline__ float bf2f(unsigned short s) {
  return __uint_as_float(((unsigned int)s) << 16);
}

// ---------------- weight pre-pack to bf16 ----------------
__global__ __launch_bounds__(256) void k_packw(const float* __restrict__ c1w,
    const float* __restrict__ c2w, const float* __restrict__ c3w,
    const float* __restrict__ Win, const float* __restrict__ Wx,
    const float* __restrict__ Wout, unsigned short* __restrict__ P) {
  int i = blockIdx.x * 256 + threadIdx.x;
  if (i >= 184320) return;
  if (i < 27648) { P[i] = f2bf(c1w[i]); return; }
  int j = i - 27648;
  if (j < 82944) {
    int cc = j / 27648, r = j - cc * 27648;
    int kk = r / 3072, r2 = r - kk * 3072;
    int oc = r2 >> 5, icl = r2 & 31;
    int ky = kk / 3, kx = kk - ky * 3;
    P[i] = f2bf(c2w[((oc * 96 + cc * 32 + icl) * 3 + ky) * 3 + kx]);
    return;
  }
  j -= 82944;
  if (j < 9216) { P[i] = f2bf(c3w[j]); return; }
  j -= 9216;
  if (j < 36864) { P[i] = f2bf(Win[j]); return; }
  j -= 36864;
  if (j < 9216) {
    int oc = j / 192, k = j - oc * 192;
    P[i] = (oc < 38) ? f2bf(Wx[oc * 192 + k]) : (unsigned short)0;
    return;
  }
  j -= 9216;
  P[i] = f2bf(Wout[j]);
}

// ---------------- generic MFMA GEMM ----------------
#define SRC_PLANAR2 0
#define SRC_ROWS    1
#define SRC_UPCAT   2   // xa = x [2,96,64,64] (bilinear 2x inline), xb = Hx [2,192,128,128]
#define OUT_BF16R    0
#define OUT_F32P     1
#define OUT_F32R     2
#define OUT_F32P_RES 4
#define OUT_XZ       5

template<int SM, int OM, int NT>
__global__ __launch_bounds__(256) void k_gemm(
    const void* __restrict__ xa, const void* __restrict__ xb, int CA,
    const unsigned short* __restrict__ Wp, const float* __restrict__ bias,
    void* __restrict__ outv, void* __restrict__ outv2, const float* __restrict__ resid,
    int K, int ostride, int ng) {
  __shared__ unsigned short x_t[128 * 96];
  __shared__ unsigned short w_t[NT * 16 * 96];
  Wp += (size_t)blockIdx.y * 96 * K;
  int pxg0 = blockIdx.x * 128;
  int b = pxg0 >> 14, px_in0 = pxg0 & 16383;
  int tid = threadIdx.x, lane = tid & 63, wv = tid >> 6;
  int r = lane & 15, q = lane >> 4;
  f4v acc[2][NT];
#pragma unroll
  for (int mi = 0; mi < 2; mi++)
#pragma unroll
    for (int n = 0; n < NT; n++) acc[mi][n] = (f4v)0.0f;
  int nchunk = K / 96;
  for (int kc = 0; kc < nchunk; kc++) {
    for (int t = tid; t < NT * 16 * 12; t += 256) {
      int row = t / 12, u8 = t - row * 12;
      *(u16x8*)&w_t[row * 96 + u8 * 8] = *(const u16x8*)&Wp[(size_t)row * K + kc * 96 + u8 * 8];
    }
    if (SM == SRC_PLANAR2) {
      const float* A0 = (const float*)xa;
      const float* A1 = (const float*)xb;
      int CB = K - CA;
      for (int t = tid; t < 3072; t += 256) {
        int px4 = t / 96, c_l = t - px4 * 96;
        int c = kc * 96 + c_l;
        const float* sp = (c < CA) ? (A0 + ((size_t)b * CA + c) * LSEQ + px_in0 + px4 * 4)
                                   : (A1 + ((size_t)b * CB + (c - CA)) * LSEQ + px_in0 + px4 * 4);
        float4 v = *(const float4*)sp;
        x_t[(px4 * 4 + 0) * 96 + c_l] = f2bf(v.x);
        x_t[(px4 * 4 + 1) * 96 + c_l] = f2bf(v.y);
        x_t[(px4 * 4 + 2) * 96 + c_l] = f2bf(v.z);
        x_t[(px4 * 4 + 3) * 96 + c_l] = f2bf(v.w);
      }
    } else if (SM == SRC_UPCAT) {
      const float* X0 = (const float*)xa;   // [2,96,64,64]
      const float* HX = (const float*)xb;   // [2,192,128,128]
      for (int t = tid; t < 3072; t += 256) {
        int px4 = t / 96, c_l = t - px4 * 96;
        int c = kc * 96 + c_l;
        int pxl = px4 * 4;
        if (c < 96) {
          int pxg = px_in0 + pxl;
          int oh = pxg >> 7, ow0 = pxg & 127;
          float pr = oh * (63.0f / 127.0f);
          int r0 = (int)pr; float rw = pr - (float)r0; int r1 = min(r0 + 1, 63);
          const float* rp0 = X0 + ((size_t)b * 96 + c) * 4096 + r0 * 64;
          const float* rp1 = X0 + ((size_t)b * 96 + c) * 4096 + r1 * 64;
#pragma unroll
          for (int g = 0; g < 4; g++) {
            int ow = ow0 + g;
            float pc = ow * (63.0f / 127.0f);
            int c0 = (int)pc; float cw = pc - (float)c0; int c1 = min(c0 + 1, 63);
            float v00 = rp0[c0], v01 = rp0[c1], v10 = rp1[c0], v11 = rp1[c1];
            float top = v00 + (v10 - v00) * rw;
            float bot = v01 + (v11 - v01) * rw;
            x_t[(pxl + g) * 96 + c_l] = f2bf(top + (bot - top) * cw);
          }
        } else {
          float4 v = *(const float4*)&HX[((size_t)b * 192 + (c - 96)) * LSEQ + px_in0 + pxl];
          x_t[(pxl + 0) * 96 + c_l] = f2bf(v.x);
          x_t[(pxl + 1) * 96 + c_l] = f2bf(v.y);
          x_t[(pxl + 2) * 96 + c_l] = f2bf(v.z);
          x_t[(pxl + 3) * 96 + c_l] = f2bf(v.w);
        }
      }
    } else {
      const unsigned short* X = (const unsigned short*)xa;
      for (int t = tid; t < 1536; t += 256) {
        int rr = t / 12, u8 = t - rr * 12;
        *(u16x8*)&x_t[rr * 96 + u8 * 8] =
            *(const u16x8*)&X[(size_t)(pxg0 + rr) * K + kc * 96 + u8 * 8];
      }
    }
    __syncthreads();
#pragma unroll
    for (int k0 = 0; k0 < 96; k0 += 32) {
      s8v a0 = *(const s8v*)&x_t[((wv * 2 + 0) * 16 + r) * 96 + k0 + q * 8];
      s8v a1 = *(const s8v*)&x_t[((wv * 2 + 1) * 16 + r) * 96 + k0 + q * 8];
#pragma unroll
      for (int n = 0; n < NT; n++) {
        s8v bb = *(const s8v*)&w_t[(n * 16 + r) * 96 + k0 + q * 8];
        acc[0][n] = __builtin_amdgcn_mfma_f32_16x16x32_bf16(a0, bb, acc[0][n], 0, 0, 0);
        acc[1][n] = __builtin_amdgcn_mfma_f32_16x16x32_bf16(a1, bb, acc[1][n], 0, 0, 0);
      }
    }
    __syncthreads();
  }
#pragma unroll
  for (int mi = 0; mi < 2; mi++) {
    int pxl = (wv * 2 + mi) * 16 + q * 4;
    int pxg = pxg0 + pxl;
#pragma unroll
    for (int n = 0; n < NT; n++) {
      int oc = n * 16 + r;
      if (OM == OUT_BF16R) {
        float bv = bias[oc];
        unsigned short* O = (unsigned short*)outv;
#pragma unroll
        for (int g = 0; g < 4; g++)
          O[(size_t)(pxg + g) * 96 + oc] = f2bf(acc[mi][n][g] + bv);
      } else if (OM == OUT_F32P) {
        float bv = bias[oc];
        float* O = (float*)outv;
        float4 o = make_float4(acc[mi][n][0] + bv, acc[mi][n][1] + bv,
                               acc[mi][n][2] + bv, acc[mi][n][3] + bv);
        *(float4*)&O[((size_t)b * 96 + oc) * LSEQ + px_in0 + pxl] = o;
      } else if (OM == OUT_F32P_RES) {
        float* O = (float*)outv;
        size_t ad = ((size_t)b * 96 + oc) * LSEQ + px_in0 + pxl;
        float4 rv = *(const float4*)&resid[ad];
        float4 o = make_float4(acc[mi][n][0] + rv.x, acc[mi][n][1] + rv.y,
                               acc[mi][n][2] + rv.z, acc[mi][n][3] + rv.w);
        *(float4*)&O[ad] = o;
      } else if (OM == OUT_F32R) {
        float* O = (float*)outv;
        int ocg = blockIdx.y * 96 + oc;
        if (ocg < ng) {
#pragma unroll
          for (int g = 0; g < 4; g++)
            O[(size_t)(pxg + g) * ostride + ocg] = acc[mi][n][g];
        }
      } else { // OUT_XZ
        int ocg = (blockIdx.y & 1) * 96 + oc;
        if (blockIdx.y < 2) {
          float* O = (float*)outv;
#pragma unroll
          for (int g = 0; g < 4; g++)
            O[(size_t)(pxg + g) * 192 + ocg] = acc[mi][n][g];
        } else {
          unsigned short* O = (unsigned short*)outv2;
#pragma unroll
          for (int g = 0; g < 4; g++)
            O[(size_t)(pxg + g) * 192 + ocg] = f2bf(acc[mi][n][g]);
        }
      }
    }
  }
}

// ---------------- conv3x3 implicit-GEMM MFMA ----------------
__global__ __launch_bounds__(256) void k_conv3x3m(const unsigned short* __restrict__ X,
    const unsigned short* __restrict__ Wp2, const float* __restrict__ bias,
    unsigned short* __restrict__ out) {
  __shared__ unsigned short in_t[3 * 68 * 32];
  __shared__ unsigned short w_t[9 * 96 * 32];
  int bi = blockIdx.x;
  int hx = bi & 1, y = (bi >> 1) & 127, b = bi >> 8;
  int px0 = hx * 64;
  int tid = threadIdx.x, lane = tid & 63, wv = tid >> 6;
  int r = lane & 15, q = lane >> 4;
  f4v acc[6];
#pragma unroll
  for (int n = 0; n < 6; n++) acc[n] = (f4v)0.0f;
  for (int cc = 0; cc < 3; cc++) {
    for (int t = tid; t < 3456; t += 256)
      *(u16x8*)&w_t[t * 8] = *(const u16x8*)&Wp2[cc * 27648 + t * 8];
    for (int t = tid; t < 792; t += 256) {
      int row = t / 264, rem = t - row * 264;
      int c_l = rem >> 2, icq = rem & 3;
      int gy = y - 1 + row, gx = px0 - 1 + c_l;
      u16x8 v = {0, 0, 0, 0, 0, 0, 0, 0};
      if (gy >= 0 && gy < 128 && gx >= 0 && gx < 128)
        v = *(const u16x8*)&X[(((size_t)b * 128 + gy) * 128 + gx) * 96 + cc * 32 + icq * 8];
      *(u16x8*)&in_t[(row * 68 + c_l) * 32 + icq * 8] = v;
    }
    __syncthreads();
#pragma unroll
    for (int kk = 0; kk < 9; kk++) {
      int ky = kk / 3, kx = kk - ky * 3;
      s8v a = *(const s8v*)&in_t[(ky * 68 + wv * 16 + r + kx) * 32 + q * 8];
#pragma unroll
      for (int n = 0; n < 6; n++) {
        s8v bb = *(const s8v*)&w_t[(kk * 96 + n * 16 + r) * 32 + q * 8];
        acc[n] = __builtin_amdgcn_mfma_f32_16x16x32_bf16(a, bb, acc[n], 0, 0, 0);
      }
    }
    __syncthreads();
  }
  size_t rowbase = ((size_t)b * 128 + y) * 128 + px0 + wv * 16 + q * 4;
#pragma unroll
  for (int n = 0; n < 6; n++) {
    int oc = n * 16 + r;
    float bv = bias[oc];
#pragma unroll
    for (int g = 0; g < 4; g++)
      out[(rowbase + g) * 96 + oc] = f2bf(acc[n][g] + bv);
  }
}

// ---------------- instance-norm stats ----------------
__global__ __launch_bounds__(256) void k_stats(const float* __restrict__ h, float* __restrict__ stats) {
  int bc = blockIdx.x;
  const float* p = h + (size_t)bc * LSEQ;
  float s = 0.f, ss = 0.f;
  for (int i = threadIdx.x; i < LSEQ; i += 256) { float v = p[i]; s += v; ss = fmaf(v, v, ss); }
  __shared__ float rs[256], rss[256];
  int tid = threadIdx.x;
  rs[tid] = s; rss[tid] = ss; __syncthreads();
  for (int o = 128; o > 0; o >>= 1) {
    if (tid < o) { rs[tid] += rs[tid + o]; rss[tid] += rss[tid + o]; }
    __syncthreads();
  }
  if (tid == 0) {
    float m = rs[0] * (1.0f / LSEQ);
    float var = rss[0] * (1.0f / LSEQ) - m * m;
    stats[bc * 2] = m;
    stats[bc * 2 + 1] = rsqrtf(fmaxf(var, 0.f) + 1e-5f);
  }
}

// ---------------- normalize + SELU ----------------
__device__ __forceinline__ float seluf(float v) {
  const float kS = 1.0507009873554805f, kSA = 1.0507009873554805f * 1.6732632423543772f;
  return v > 0.f ? kS * v : kSA * (__expf(v) - 1.f);
}
__global__ __launch_bounds__(256) void k_normselu2(const float* __restrict__ h,
    const float* __restrict__ stats, float* __restrict__ Lx, unsigned short* __restrict__ LxR) {
  __shared__ float tile[96 * 65];
  int px0 = blockIdx.x * 64, b = blockIdx.y;
  int tid = threadIdx.x;
  for (int t = tid; t < 1536; t += 256) {
    int c = t >> 4, p4 = t & 15;
    size_t ga = ((size_t)b * 96 + c) * LSEQ + px0 + p4 * 4;
    float4 v = *(const float4*)&h[ga];
    float m = stats[(b * 96 + c) * 2], rv = stats[(b * 96 + c) * 2 + 1];
    v.x = seluf((v.x - m) * rv);
    v.y = seluf((v.y - m) * rv);
    v.z = seluf((v.z - m) * rv);
    v.w = seluf((v.w - m) * rv);
    *(float4*)&Lx[ga] = v;
    tile[c * 65 + p4 * 4 + 0] = v.x;
    tile[c * 65 + p4 * 4 + 1] = v.y;
    tile[c * 65 + p4 * 4 + 2] = v.z;
    tile[c * 65 + p4 * 4 + 3] = v.w;
  }
  __syncthreads();
  for (int t = tid; t < 768; t += 256) {
    int px = t / 12, c8 = t - px * 12;
    u16x8 o;
#pragma unroll
    for (int jj = 0; jj < 8; jj++) o[jj] = f2bf(tile[(c8 * 8 + jj) * 65 + px]);
    *(u16x8*)&LxR[((size_t)b * LSEQ + px0 + px) * 96 + c8 * 8] = o;
  }
}

// ---------------- causal depthwise conv1d + SiLU ----------------
__global__ __launch_bounds__(256) void k_conv1d(const float* __restrict__ xzx,
    const float* __restrict__ w1d, const float* __restrict__ b1d,
    float* __restrict__ u, unsigned short* __restrict__ uR) {
  int gid = blockIdx.x * 256 + threadIdx.x;
  if (gid >= 2 * LSEQ * DIN) return;
  int d = gid % DIN, bl = gid / DIN;
  int l = bl & (LSEQ - 1);
  float4 w = *(const float4*)&w1d[d * 4];
  float wv[4] = {w.x, w.y, w.z, w.w};
  float acc = b1d[d];
#pragma unroll
  for (int k = 0; k < 4; k++) {
    int lk = l - 3 + k;
    if (lk >= 0) acc = fmaf(wv[k], xzx[(size_t)(bl - 3 + k) * DIN + d], acc);
  }
  float s = siluf(acc);
  u[gid] = s;
  uR[gid] = f2bf(s);
}

// ---------------- scan phase A: per-chunk (prod a, h_end), dt fused ----------------
// R9: main t-loop fully unrolled so uu[]/dtv[] are statically indexed -> true
// registers (R8 left the loop rolled; dynamic indexing spilled both arrays to
// scratch: VGPR=48, +24MB scratch writes/dispatch).
__global__ __launch_bounds__(192, 3) void k_scanA(const float* __restrict__ u,
    const float* __restrict__ xdbl, const float* __restrict__ Wdt,
    const float* __restrict__ bdt, const float* __restrict__ Alog,
    float* __restrict__ chA, float* __restrict__ chB) {
  int b = blockIdx.y, g = blockIdx.x, d = threadIdx.x;
  __shared__ float Bs[TCH * 16], Dts[TCH * 8];
  for (int i = d; i < TCH * 16; i += 192) {
    int t = i >> 4, n = i & 15;
    Bs[i] = xdbl[(size_t)(b * LSEQ + g * TCH + t) * 38 + 6 + n];
  }
  for (int i = d; i < TCH * 6; i += 192) {
    int t = i / 6, c = i - t * 6;
    Dts[t * 8 + c] = xdbl[(size_t)(b * LSEQ + g * TCH + t) * 38 + c];
  }
  float ac2[16];
#pragma unroll
  for (int n = 0; n < 16; n++) ac2[n] = -__expf(Alog[d * 16 + n]) * 1.44269504f;
  float wdt[6];
#pragma unroll
  for (int c = 0; c < 6; c++) wdt[c] = Wdt[d * 6 + c];
  float bd = bdt[d];
  size_t base0 = (size_t)(b * LSEQ + g * TCH);
  float uu[TCH];
#pragma unroll
  for (int t = 0; t < TCH; t++) uu[t] = u[(base0 + t) * DIN + d];
  __syncthreads();
  float dtv[TCH];
#pragma unroll
  for (int t = 0; t < TCH; t++) {
    float dr = bd;
#pragma unroll
    for (int c = 0; c < 6; c++) dr = fmaf(Dts[t * 8 + c], wdt[c], dr);
    dtv[t] = dr > 20.f ? dr : __logf(1.f + __expf(dr));
  }
  float ap[16], hb[16];
#pragma unroll
  for (int n = 0; n < 16; n++) { ap[n] = 1.f; hb[n] = 0.f; }
#pragma unroll
  for (int t = 0; t < TCH; t++) {
    float du = dtv[t] * uu[t];
    float bs[16];
    const float4* src = (const float4*)&Bs[t * 16];
#pragma unroll
    for (int qq = 0; qq < 4; qq++) {
      float4 v = src[qq];
      bs[qq * 4] = v.x; bs[qq * 4 + 1] = v.y; bs[qq * 4 + 2] = v.z; bs[qq * 4 + 3] = v.w;
    }
#pragma unroll
    for (int n = 0; n < 16; n++) {
      float e = fexp2(dtv[t] * ac2[n]);
      ap[n] *= e;
      hb[n] = fmaf(hb[n], e, du * bs[n]);
    }
  }
  size_t co = ((size_t)(b * GCH + g) * DIN + d) * 16;
#pragma unroll
  for (int qq = 0; qq < 4; qq++) {
    ((float4*)(chA + co))[qq] = make_float4(ap[qq * 4], ap[qq * 4 + 1], ap[qq * 4 + 2], ap[qq * 4 + 3]);
    ((float4*)(chB + co))[qq] = make_float4(hb[qq * 4], hb[qq * 4 + 1], hb[qq * 4 + 2], hb[qq * 4 + 3]);
  }
}

// ---------------- scan phase B: block-parallel cross-chunk scan ----------------
__global__ __launch_bounds__(256) void k_scanB(const float* __restrict__ chA,
    const float* __restrict__ chB, float* __restrict__ h0) {
  __shared__ float sa[16 * 17], sb[16 * 17];
  int blk = blockIdx.x;
  int b = blk / DIN, d = blk - b * DIN;
  int tid = threadIdx.x;
  int seg = tid >> 4, n = tid & 15;
  float ca[32], cb[32];
  float aagg = 1.f, bagg = 0.f;
#pragma unroll 8
  for (int j = 0; j < 32; j++) {
    int g = seg * 32 + j;
    size_t off = ((size_t)(b * GCH + g) * DIN + d) * 16 + n;
    float a = chA[off], bb = chB[off];
    ca[j] = a; cb[j] = bb;
    bagg = fmaf(a, bagg, bb);
    aagg *= a;
  }
  sa[n * 17 + seg] = aagg;
  sb[n * 17 + seg] = bagg;
  __syncthreads();
  if (tid < 16) {
    float pa = 1.f, pb = 0.f;
#pragma unroll
    for (int s = 0; s < 16; s++) {
      float ta = sa[tid * 17 + s], tb = sb[tid * 17 + s];
      sa[tid * 17 + s] = pa;
      sb[tid * 17 + s] = pb;
      pb = fmaf(ta, pb, tb);
      pa *= ta;
    }
  }
  __syncthreads();
  float h = sb[n * 17 + seg];
#pragma unroll 8
  for (int j = 0; j < 32; j++) {
    int g = seg * 32 + j;
    size_t off = ((size_t)(b * GCH + g) * DIN + d) * 16 + n;
    h0[off] = h;
    h = fmaf(ca[j], h, cb[j]);
  }
}

// ---------------- scan phase C: replay + gate, dt fused ----------------
__global__ __launch_bounds__(192, 3) void k_scanC(const float* __restrict__ u,
    const float* __restrict__ xdbl, const float* __restrict__ Wdt,
    const float* __restrict__ bdt, const unsigned short* __restrict__ zR,
    const float* __restrict__ Alog, const float* __restrict__ Dp,
    const float* __restrict__ h0, unsigned short* __restrict__ yR) {
  int b = blockIdx.y, g = blockIdx.x, d = threadIdx.x;
  __shared__ float Bs[TCH * 16], Cs[TCH * 16], Dts[TCH * 8];
  for (int i = d; i < TCH * 16; i += 192) {
    int t = i >> 4, n = i & 15;
    size_t rb = (size_t)(b * LSEQ + g * TCH + t) * 38;
    Bs[i] = xdbl[rb + 6 + n];
    Cs[i] = xdbl[rb + 22 + n];
  }
  for (int i = d; i < TCH * 6; i += 192) {
    int t = i / 6, c = i - t * 6;
    Dts[t * 8 + c] = xdbl[(size_t)(b * LSEQ + g * TCH + t) * 38 + c];
  }
  float ac2[16];
#pragma unroll
  for (int n = 0; n < 16; n++) ac2[n] = -__expf(Alog[d * 16 + n]) * 1.44269504f;
  float wdt[6];
#pragma unroll
  for (int c = 0; c < 6; c++) wdt[c] = Wdt[d * 6 + c];
  float bd = bdt[d];
  float Dd = Dp[d];
  size_t base0 = (size_t)(b * LSEQ + g * TCH);
  float uu[TCH];
#pragma unroll
  for (int t = 0; t < TCH; t++) uu[t] = u[(base0 + t) * DIN + d];
  size_t co = ((size_t)(b * GCH + g) * DIN + d) * 16;
  float h[16];
#pragma unroll
  for (int qq = 0; qq < 4; qq++) {
    float4 v = ((const float4*)(h0 + co))[qq];
    h[qq * 4] = v.x; h[qq * 4 + 1] = v.y; h[qq * 4 + 2] = v.z; h[qq * 4 + 3] = v.w;
  }
  __syncthreads();
  float dtv[TCH];
#pragma unroll
  for (int t = 0; t < TCH; t++) {
    float dr = bd;
#pragma unroll
    for (int c = 0; c < 6; c++) dr = fmaf(Dts[t * 8 + c], wdt[c], dr);
    dtv[t] = dr > 20.f ? dr : __logf(1.f + __expf(dr));
  }
#pragma unroll
  for (int t = 0; t < TCH; t++) {
    float du = dtv[t] * uu[t];
    float zv = bf2f(zR[(base0 + t) * DIN + d]);
    float bs[16], cs[16];
    const float4* sbp = (const float4*)&Bs[t * 16];
    const float4* scp = (const float4*)&Cs[t * 16];
#pragma unroll
    for (int qq = 0; qq < 4; qq++) {
      float4 vb = sbp[qq], vc = scp[qq];
      bs[qq * 4] = vb.x; bs[qq * 4 + 1] = vb.y; bs[qq * 4 + 2] = vb.z; bs[qq * 4 + 3] = vb.w;
      cs[qq * 4] = vc.x; cs[qq * 4 + 1] = vc.y; cs[qq * 4 + 2] = vc.z; cs[qq * 4 + 3] = vc.w;
    }
    float y0 = 0.f, y1 = 0.f, y2 = 0.f, y3 = 0.f;
#pragma unroll
    for (int n = 0; n < 16; n++) {
      float e = fexp2(dtv[t] * ac2[n]);
      h[n] = fmaf(h[n], e, du * bs[n]);
      float p = h[n] * cs[n];
      if ((n & 3) == 0) y0 += p; else if ((n & 3) == 1) y1 += p;
      else if ((n & 3) == 2) y2 += p; else y3 += p;
    }
    float yv = ((y0 + y1) + (y2 + y3)) + uu[t] * Dd;
    yR[(base0 + t) * DIN + d] = f2bf(yv * siluf(zv));
  }
}

// ---------------- launch ----------------
extern "C" void kernel_launch(void* const* d_in, const int* in_sizes, int n_in,
                              void* d_out, int out_size, void* d_ws, size_t ws_size,
                              hipStream_t stream) {
  (void)in_sizes; (void)n_in; (void)out_size; (void)ws_size;
  const float* x    = (const float*)d_in[0];
  const float* Hx   = (const float*)d_in[1];
  const float* c1w  = (const float*)d_in[2];
  const float* c1b  = (const float*)d_in[3];
  const float* c2w  = (const float*)d_in[4];
  const float* c2b  = (const float*)d_in[5];
  const float* c3w  = (const float*)d_in[6];
  const float* c3b  = (const float*)d_in[7];
  const float* Win  = (const float*)d_in[8];
  const float* w1d  = (const float*)d_in[9];
  const float* b1d  = (const float*)d_in[10];
  const float* Wx   = (const float*)d_in[11];
  const float* Wdt  = (const float*)d_in[12];
  const float* bdt  = (const float*)d_in[13];
  const float* Alog = (const float*)d_in[14];
  const float* Dp   = (const float*)d_in[15];
  const float* Wout = (const float*)d_in[16];
  float* out = (float*)d_out;

  float* ws = (float*)d_ws;
  const size_t F = (size_t)2 * 96 * LSEQ;
  const size_t Fh = F / 2;

  float*          b_h3 = ws;
  float*          chA  = ws;
  float*          b_Lx = ws + F;
  unsigned short* R1   = (unsigned short*)(ws + 2 * F);
  unsigned short* R2   = (unsigned short*)(ws + 2 * F + Fh);
  float*          xdbl = ws + 2 * F + Fh;
  float*          xzx  = ws + 3 * F;
  float*          chB  = ws + 3 * F;
  float*          h0b  = ws + 4 * F;
  unsigned short* zRb  = (unsigned short*)(ws + 5 * F);
  unsigned short* R3   = (unsigned short*)(ws + 6 * F);
  float*          b_u  = ws + 7 * F;
  unsigned short* Wp   = (unsigned short*)(ws + 9 * F);
  float*          b_st = ws + 9 * F + 92160;

  k_packw<<<dim3(720), dim3(256), 0, stream>>>(c1w, c2w, c3w, Win, Wx, Wout, Wp);
  k_gemm<SRC_UPCAT, OUT_BF16R, 6><<<dim3(256, 1), dim3(256), 0, stream>>>(
      x, Hx, 96, Wp, c1b, R1, nullptr, nullptr, 288, 0, 0);
  k_conv3x3m<<<dim3(512), dim3(256), 0, stream>>>(R1, Wp + 27648, c2b, R2);
  k_gemm<SRC_ROWS, OUT_F32P, 6><<<dim3(256, 1), dim3(256), 0, stream>>>(
      R2, nullptr, 0, Wp + 110592, c3b, b_h3, nullptr, nullptr, 96, 0, 0);
  k_stats<<<dim3(192), dim3(256), 0, stream>>>(b_h3, b_st);
  k_normselu2<<<dim3(256, 2), dim3(256), 0, stream>>>(b_h3, b_st, b_Lx, R1);
  k_gemm<SRC_ROWS, OUT_XZ, 6><<<dim3(256, 4), dim3(256), 0, stream>>>(
      R1, nullptr, 0, Wp + 119808, nullptr, xzx, zRb, nullptr, 96, 192, 0);
  k_conv1d<<<dim3((2 * LSEQ * DIN + 255) / 256), dim3(256), 0, stream>>>(xzx, w1d, b1d, b_u, R3);
  k_gemm<SRC_ROWS, OUT_F32R, 3><<<dim3(256, 1), dim3(256), 0, stream>>>(
      R3, nullptr, 0, Wp + 156672, nullptr, xdbl, nullptr, nullptr, 192, 38, 38);
  k_scanA<<<dim3(GCH, 2), dim3(192), 0, stream>>>(b_u, xdbl, Wdt, bdt, Alog, chA, chB);
  k_scanB<<<dim3(2 * DIN), dim3(256), 0, stream>>>(chA, chB, h0b);
  k_scanC<<<dim3(GCH, 2), dim3(192), 0, stream>>>(b_u, xdbl, Wdt, bdt, zRb, Alog, Dp, h0b, R3);
  k_gemm<SRC_ROWS, OUT_F32P_RES, 6><<<dim3(256, 1), dim3(256), 0, stream>>>(
      R3, nullptr, 0, Wp + 165888, nullptr, out, nullptr, b_Lx, 192, 0, 0);
}

// Round 10
// 333.857 us; speedup vs baseline: 1.2758x; 1.0406x over previous
//
#include <hip/hip_runtime.h>
#include <hip/hip_bf16.h>
#include <math.h>

#define LSEQ 16384
#define DIN  192
#define GCH  512
#define TCH  32

typedef float f4v __attribute__((ext_vector_type(4)));
typedef short s8v __attribute__((ext_vector_type(8)));
typedef unsigned short u16x8 __attribute__((ext_vector_type(8)));

__device__ __forceinline__ float siluf(float x) { return __fdividef(x, 1.0f + __expf(-x)); }
__device__ __forceinline__ float fexp2(float x) {
#if __has_builtin(__builtin_amdgcn_exp2f)
  return __builtin_amdgcn_exp2f(x);
#else
  return __expf(x * 0.69314718056f);
#endif
}
__device__ __forceinline__ unsigned short f2bf(float f) {
  unsigned int u = __float_as_uint(f);
  unsigned int r = (u + 0x7FFFu + ((u >> 16) & 1u)) >> 16;
  return (unsigned short)r;
}
__device__ __forceinline__ float bf2f(unsigned short s) {
  return __uint_as_float(((unsigned int)s) << 16);
}

// ---------------- weight pre-pack to bf16 ----------------
__global__ __launch_bounds__(256) void k_packw(const float* __restrict__ c1w,
    const float* __restrict__ c2w, const float* __restrict__ c3w,
    const float* __restrict__ Win, const float* __restrict__ Wx,
    const float* __restrict__ Wout, unsigned short* __restrict__ P) {
  int i = blockIdx.x * 256 + threadIdx.x;
  if (i >= 184320) return;
  if (i < 27648) { P[i] = f2bf(c1w[i]); return; }
  int j = i - 27648;
  if (j < 82944) {
    int cc = j / 27648, r = j - cc * 27648;
    int kk = r / 3072, r2 = r - kk * 3072;
    int oc = r2 >> 5, icl = r2 & 31;
    int ky = kk / 3, kx = kk - ky * 3;
    P[i] = f2bf(c2w[((oc * 96 + cc * 32 + icl) * 3 + ky) * 3 + kx]);
    return;
  }
  j -= 82944;
  if (j < 9216) { P[i] = f2bf(c3w[j]); return; }
  j -= 9216;
  if (j < 36864) { P[i] = f2bf(Win[j]); return; }
  j -= 36864;
  if (j < 9216) {
    int oc = j / 192, k = j - oc * 192;
    P[i] = (oc < 38) ? f2bf(Wx[oc * 192 + k]) : (unsigned short)0;
    return;
  }
  j -= 9216;
  P[i] = f2bf(Wout[j]);
}

// ---------------- upsample 2x + concat Hx -> bf16 rows [32768][288] ----------------
// R10: LDS-tiled transpose (both global sides coalesced). Replaces SRC_UPCAT,
// whose channel-major staging was a 64-way stride-LSEQ scatter (43us conv1).
__global__ __launch_bounds__(256) void k_upcat(const float* __restrict__ x,
    const float* __restrict__ Hx, unsigned short* __restrict__ UH) {
  __shared__ float tile[96 * 65];
  int px0 = blockIdx.x * 64, b = blockIdx.y;
  int tid = threadIdx.x;
  for (int cg = 0; cg < 3; cg++) {
    if (cg == 0) {
      int oh = px0 >> 7, owbase = px0 & 127;
      float pr = oh * (63.0f / 127.0f);
      int r0 = (int)pr; float rw = pr - (float)r0; int r1 = min(r0 + 1, 63);
      for (int t = tid; t < 1536; t += 256) {
        int c = t >> 4, p4 = t & 15;
        const float* rp0 = x + ((size_t)b * 96 + c) * 4096 + r0 * 64;
        const float* rp1 = x + ((size_t)b * 96 + c) * 4096 + r1 * 64;
#pragma unroll
        for (int g = 0; g < 4; g++) {
          int ow = owbase + p4 * 4 + g;
          float pc = ow * (63.0f / 127.0f);
          int c0 = (int)pc; float cw = pc - (float)c0; int c1 = min(c0 + 1, 63);
          float v00 = rp0[c0], v01 = rp0[c1], v10 = rp1[c0], v11 = rp1[c1];
          float top = v00 + (v10 - v00) * rw;
          float bot = v01 + (v11 - v01) * rw;
          tile[c * 65 + p4 * 4 + g] = top + (bot - top) * cw;
        }
      }
    } else {
      for (int t = tid; t < 1536; t += 256) {
        int c = t >> 4, p4 = t & 15;
        float4 v = *(const float4*)&Hx[((size_t)b * 192 + (cg - 1) * 96 + c) * LSEQ + px0 + p4 * 4];
        tile[c * 65 + p4 * 4 + 0] = v.x;
        tile[c * 65 + p4 * 4 + 1] = v.y;
        tile[c * 65 + p4 * 4 + 2] = v.z;
        tile[c * 65 + p4 * 4 + 3] = v.w;
      }
    }
    __syncthreads();
    for (int t = tid; t < 768; t += 256) {
      int px = t / 12, c8 = t - px * 12;
      u16x8 o;
#pragma unroll
      for (int jj = 0; jj < 8; jj++) o[jj] = f2bf(tile[(c8 * 8 + jj) * 65 + px]);
      *(u16x8*)&UH[((size_t)b * LSEQ + px0 + px) * 288 + cg * 96 + c8 * 8] = o;
    }
    __syncthreads();
  }
}

// ---------------- generic MFMA GEMM (rows source) ----------------
#define OUT_BF16R    0
#define OUT_F32P     1
#define OUT_F32R     2
#define OUT_F32P_RES 4
#define OUT_XZ       5

template<int OM, int NT>
__global__ __launch_bounds__(256) void k_gemm(
    const unsigned short* __restrict__ X,
    const unsigned short* __restrict__ Wp, const float* __restrict__ bias,
    void* __restrict__ outv, void* __restrict__ outv2, const float* __restrict__ resid,
    int K, int ostride, int ng) {
  __shared__ unsigned short x_t[128 * 96];
  __shared__ unsigned short w_t[NT * 16 * 96];
  Wp += (size_t)blockIdx.y * 96 * K;
  int pxg0 = blockIdx.x * 128;
  int b = pxg0 >> 14, px_in0 = pxg0 & 16383;
  int tid = threadIdx.x, lane = tid & 63, wv = tid >> 6;
  int r = lane & 15, q = lane >> 4;
  f4v acc[2][NT];
#pragma unroll
  for (int mi = 0; mi < 2; mi++)
#pragma unroll
    for (int n = 0; n < NT; n++) acc[mi][n] = (f4v)0.0f;
  int nchunk = K / 96;
  for (int kc = 0; kc < nchunk; kc++) {
    for (int t = tid; t < NT * 16 * 12; t += 256) {
      int row = t / 12, u8 = t - row * 12;
      *(u16x8*)&w_t[row * 96 + u8 * 8] = *(const u16x8*)&Wp[(size_t)row * K + kc * 96 + u8 * 8];
    }
    for (int t = tid; t < 1536; t += 256) {
      int rr = t / 12, u8 = t - rr * 12;
      *(u16x8*)&x_t[rr * 96 + u8 * 8] =
          *(const u16x8*)&X[(size_t)(pxg0 + rr) * K + kc * 96 + u8 * 8];
    }
    __syncthreads();
#pragma unroll
    for (int k0 = 0; k0 < 96; k0 += 32) {
      s8v a0 = *(const s8v*)&x_t[((wv * 2 + 0) * 16 + r) * 96 + k0 + q * 8];
      s8v a1 = *(const s8v*)&x_t[((wv * 2 + 1) * 16 + r) * 96 + k0 + q * 8];
#pragma unroll
      for (int n = 0; n < NT; n++) {
        s8v bb = *(const s8v*)&w_t[(n * 16 + r) * 96 + k0 + q * 8];
        acc[0][n] = __builtin_amdgcn_mfma_f32_16x16x32_bf16(a0, bb, acc[0][n], 0, 0, 0);
        acc[1][n] = __builtin_amdgcn_mfma_f32_16x16x32_bf16(a1, bb, acc[1][n], 0, 0, 0);
      }
    }
    __syncthreads();
  }
#pragma unroll
  for (int mi = 0; mi < 2; mi++) {
    int pxl = (wv * 2 + mi) * 16 + q * 4;
    int pxg = pxg0 + pxl;
#pragma unroll
    for (int n = 0; n < NT; n++) {
      int oc = n * 16 + r;
      if (OM == OUT_BF16R) {
        float bv = bias[oc];
        unsigned short* O = (unsigned short*)outv;
#pragma unroll
        for (int g = 0; g < 4; g++)
          O[(size_t)(pxg + g) * 96 + oc] = f2bf(acc[mi][n][g] + bv);
      } else if (OM == OUT_F32P) {
        float bv = bias[oc];
        float* O = (float*)outv;
        float4 o = make_float4(acc[mi][n][0] + bv, acc[mi][n][1] + bv,
                               acc[mi][n][2] + bv, acc[mi][n][3] + bv);
        *(float4*)&O[((size_t)b * 96 + oc) * LSEQ + px_in0 + pxl] = o;
      } else if (OM == OUT_F32P_RES) {
        float* O = (float*)outv;
        size_t ad = ((size_t)b * 96 + oc) * LSEQ + px_in0 + pxl;
        float4 rv = *(const float4*)&resid[ad];
        float4 o = make_float4(acc[mi][n][0] + rv.x, acc[mi][n][1] + rv.y,
                               acc[mi][n][2] + rv.z, acc[mi][n][3] + rv.w);
        *(float4*)&O[ad] = o;
      } else if (OM == OUT_F32R) {
        float* O = (float*)outv;
        int ocg = blockIdx.y * 96 + oc;
        if (ocg < ng) {
#pragma unroll
          for (int g = 0; g < 4; g++)
            O[(size_t)(pxg + g) * ostride + ocg] = acc[mi][n][g];
        }
      } else { // OUT_XZ
        int ocg = (blockIdx.y & 1) * 96 + oc;
        if (blockIdx.y < 2) {
          float* O = (float*)outv;
#pragma unroll
          for (int g = 0; g < 4; g++)
            O[(size_t)(pxg + g) * 192 + ocg] = acc[mi][n][g];
        } else {
          unsigned short* O = (unsigned short*)outv2;
#pragma unroll
          for (int g = 0; g < 4; g++)
            O[(size_t)(pxg + g) * 192 + ocg] = f2bf(acc[mi][n][g]);
        }
      }
    }
  }
}

// ---------------- conv3x3 implicit-GEMM MFMA ----------------
__global__ __launch_bounds__(256) void k_conv3x3m(const unsigned short* __restrict__ X,
    const unsigned short* __restrict__ Wp2, const float* __restrict__ bias,
    unsigned short* __restrict__ out) {
  __shared__ unsigned short in_t[3 * 68 * 32];
  __shared__ unsigned short w_t[9 * 96 * 32];
  int bi = blockIdx.x;
  int hx = bi & 1, y = (bi >> 1) & 127, b = bi >> 8;
  int px0 = hx * 64;
  int tid = threadIdx.x, lane = tid & 63, wv = tid >> 6;
  int r = lane & 15, q = lane >> 4;
  f4v acc[6];
#pragma unroll
  for (int n = 0; n < 6; n++) acc[n] = (f4v)0.0f;
  for (int cc = 0; cc < 3; cc++) {
    for (int t = tid; t < 3456; t += 256)
      *(u16x8*)&w_t[t * 8] = *(const u16x8*)&Wp2[cc * 27648 + t * 8];
    for (int t = tid; t < 792; t += 256) {
      int row = t / 264, rem = t - row * 264;
      int c_l = rem >> 2, icq = rem & 3;
      int gy = y - 1 + row, gx = px0 - 1 + c_l;
      u16x8 v = {0, 0, 0, 0, 0, 0, 0, 0};
      if (gy >= 0 && gy < 128 && gx >= 0 && gx < 128)
        v = *(const u16x8*)&X[(((size_t)b * 128 + gy) * 128 + gx) * 96 + cc * 32 + icq * 8];
      *(u16x8*)&in_t[(row * 68 + c_l) * 32 + icq * 8] = v;
    }
    __syncthreads();
#pragma unroll
    for (int kk = 0; kk < 9; kk++) {
      int ky = kk / 3, kx = kk - ky * 3;
      s8v a = *(const s8v*)&in_t[(ky * 68 + wv * 16 + r + kx) * 32 + q * 8];
#pragma unroll
      for (int n = 0; n < 6; n++) {
        s8v bb = *(const s8v*)&w_t[(kk * 96 + n * 16 + r) * 32 + q * 8];
        acc[n] = __builtin_amdgcn_mfma_f32_16x16x32_bf16(a, bb, acc[n], 0, 0, 0);
      }
    }
    __syncthreads();
  }
  size_t rowbase = ((size_t)b * 128 + y) * 128 + px0 + wv * 16 + q * 4;
#pragma unroll
  for (int n = 0; n < 6; n++) {
    int oc = n * 16 + r;
    float bv = bias[oc];
#pragma unroll
    for (int g = 0; g < 4; g++)
      out[(rowbase + g) * 96 + oc] = f2bf(acc[n][g] + bv);
  }
}

// ---------------- instance-norm stats ----------------
__global__ __launch_bounds__(256) void k_stats(const float* __restrict__ h, float* __restrict__ stats) {
  int bc = blockIdx.x;
  const float* p = h + (size_t)bc * LSEQ;
  float s = 0.f, ss = 0.f;
  for (int i = threadIdx.x; i < LSEQ; i += 256) { float v = p[i]; s += v; ss = fmaf(v, v, ss); }
  __shared__ float rs[256], rss[256];
  int tid = threadIdx.x;
  rs[tid] = s; rss[tid] = ss; __syncthreads();
  for (int o = 128; o > 0; o >>= 1) {
    if (tid < o) { rs[tid] += rs[tid + o]; rss[tid] += rss[tid + o]; }
    __syncthreads();
  }
  if (tid == 0) {
    float m = rs[0] * (1.0f / LSEQ);
    float var = rss[0] * (1.0f / LSEQ) - m * m;
    stats[bc * 2] = m;
    stats[bc * 2 + 1] = rsqrtf(fmaxf(var, 0.f) + 1e-5f);
  }
}

// ---------------- normalize + SELU ----------------
__device__ __forceinline__ float seluf(float v) {
  const float kS = 1.0507009873554805f, kSA = 1.0507009873554805f * 1.6732632423543772f;
  return v > 0.f ? kS * v : kSA * (__expf(v) - 1.f);
}
__global__ __launch_bounds__(256) void k_normselu2(const float* __restrict__ h,
    const float* __restrict__ stats, float* __restrict__ Lx, unsigned short* __restrict__ LxR) {
  __shared__ float tile[96 * 65];
  int px0 = blockIdx.x * 64, b = blockIdx.y;
  int tid = threadIdx.x;
  for (int t = tid; t < 1536; t += 256) {
    int c = t >> 4, p4 = t & 15;
    size_t ga = ((size_t)b * 96 + c) * LSEQ + px0 + p4 * 4;
    float4 v = *(const float4*)&h[ga];
    float m = stats[(b * 96 + c) * 2], rv = stats[(b * 96 + c) * 2 + 1];
    v.x = seluf((v.x - m) * rv);
    v.y = seluf((v.y - m) * rv);
    v.z = seluf((v.z - m) * rv);
    v.w = seluf((v.w - m) * rv);
    *(float4*)&Lx[ga] = v;
    tile[c * 65 + p4 * 4 + 0] = v.x;
    tile[c * 65 + p4 * 4 + 1] = v.y;
    tile[c * 65 + p4 * 4 + 2] = v.z;
    tile[c * 65 + p4 * 4 + 3] = v.w;
  }
  __syncthreads();
  for (int t = tid; t < 768; t += 256) {
    int px = t / 12, c8 = t - px * 12;
    u16x8 o;
#pragma unroll
    for (int jj = 0; jj < 8; jj++) o[jj] = f2bf(tile[(c8 * 8 + jj) * 65 + px]);
    *(u16x8*)&LxR[((size_t)b * LSEQ + px0 + px) * 96 + c8 * 8] = o;
  }
}

// ---------------- causal depthwise conv1d + SiLU (bf16 out only) ----------------
__global__ __launch_bounds__(256) void k_conv1d(const float* __restrict__ xzx,
    const float* __restrict__ w1d, const float* __restrict__ b1d,
    unsigned short* __restrict__ uR) {
  int gid = blockIdx.x * 256 + threadIdx.x;
  if (gid >= 2 * LSEQ * DIN) return;
  int d = gid % DIN, bl = gid / DIN;
  int l = bl & (LSEQ - 1);
  float4 w = *(const float4*)&w1d[d * 4];
  float wv[4] = {w.x, w.y, w.z, w.w};
  float acc = b1d[d];
#pragma unroll
  for (int k = 0; k < 4; k++) {
    int lk = l - 3 + k;
    if (lk >= 0) acc = fmaf(wv[k], xzx[(size_t)(bl - 3 + k) * DIN + d], acc);
  }
  uR[gid] = f2bf(siluf(acc));
}

// ---------------- scan phase A: per-chunk (prod a, h_end), dt fused ----------------
__global__ __launch_bounds__(192, 3) void k_scanA(const unsigned short* __restrict__ uR,
    const float* __restrict__ xdbl, const float* __restrict__ Wdt,
    const float* __restrict__ bdt, const float* __restrict__ Alog,
    float* __restrict__ chA, float* __restrict__ chB) {
  int b = blockIdx.y, g = blockIdx.x, d = threadIdx.x;
  __shared__ float Bs[TCH * 16], Dts[TCH * 8];
  for (int i = d; i < TCH * 16; i += 192) {
    int t = i >> 4, n = i & 15;
    Bs[i] = xdbl[(size_t)(b * LSEQ + g * TCH + t) * 38 + 6 + n];
  }
  for (int i = d; i < TCH * 6; i += 192) {
    int t = i / 6, c = i - t * 6;
    Dts[t * 8 + c] = xdbl[(size_t)(b * LSEQ + g * TCH + t) * 38 + c];
  }
  float ac2[16];
#pragma unroll
  for (int n = 0; n < 16; n++) ac2[n] = -__expf(Alog[d * 16 + n]) * 1.44269504f;
  float wdt[6];
#pragma unroll
  for (int c = 0; c < 6; c++) wdt[c] = Wdt[d * 6 + c];
  float bd = bdt[d];
  size_t base0 = (size_t)(b * LSEQ + g * TCH);
  float uu[TCH];
#pragma unroll
  for (int t = 0; t < TCH; t++) uu[t] = bf2f(uR[(base0 + t) * DIN + d]);
  __syncthreads();
  float dtv[TCH];
#pragma unroll
  for (int t = 0; t < TCH; t++) {
    float dr = bd;
#pragma unroll
    for (int c = 0; c < 6; c++) dr = fmaf(Dts[t * 8 + c], wdt[c], dr);
    dtv[t] = dr > 20.f ? dr : __logf(1.f + __expf(dr));
  }
  float ap[16], hb[16];
#pragma unroll
  for (int n = 0; n < 16; n++) { ap[n] = 1.f; hb[n] = 0.f; }
#pragma unroll
  for (int t = 0; t < TCH; t++) {
    float du = dtv[t] * uu[t];
    float bs[16];
    const float4* src = (const float4*)&Bs[t * 16];
#pragma unroll
    for (int qq = 0; qq < 4; qq++) {
      float4 v = src[qq];
      bs[qq * 4] = v.x; bs[qq * 4 + 1] = v.y; bs[qq * 4 + 2] = v.z; bs[qq * 4 + 3] = v.w;
    }
#pragma unroll
    for (int n = 0; n < 16; n++) {
      float e = fexp2(dtv[t] * ac2[n]);
      ap[n] *= e;
      hb[n] = fmaf(hb[n], e, du * bs[n]);
    }
  }
  size_t co = ((size_t)(b * GCH + g) * DIN + d) * 16;
#pragma unroll
  for (int qq = 0; qq < 4; qq++) {
    ((float4*)(chA + co))[qq] = make_float4(ap[qq * 4], ap[qq * 4 + 1], ap[qq * 4 + 2], ap[qq * 4 + 3]);
    ((float4*)(chB + co))[qq] = make_float4(hb[qq * 4], hb[qq * 4 + 1], hb[qq * 4 + 2], hb[qq * 4 + 3]);
  }
}

// ---------------- scan phase B: block-parallel cross-chunk scan ----------------
__global__ __launch_bounds__(256) void k_scanB(const float* __restrict__ chA,
    const float* __restrict__ chB, float* __restrict__ h0) {
  __shared__ float sa[16 * 17], sb[16 * 17];
  int blk = blockIdx.x;
  int b = blk / DIN, d = blk - b * DIN;
  int tid = threadIdx.x;
  int seg = tid >> 4, n = tid & 15;
  float ca[32], cb[32];
  float aagg = 1.f, bagg = 0.f;
#pragma unroll 8
  for (int j = 0; j < 32; j++) {
    int g = seg * 32 + j;
    size_t off = ((size_t)(b * GCH + g) * DIN + d) * 16 + n;
    float a = chA[off], bb = chB[off];
    ca[j] = a; cb[j] = bb;
    bagg = fmaf(a, bagg, bb);
    aagg *= a;
  }
  sa[n * 17 + seg] = aagg;
  sb[n * 17 + seg] = bagg;
  __syncthreads();
  if (tid < 16) {
    float pa = 1.f, pb = 0.f;
#pragma unroll
    for (int s = 0; s < 16; s++) {
      float ta = sa[tid * 17 + s], tb = sb[tid * 17 + s];
      sa[tid * 17 + s] = pa;
      sb[tid * 17 + s] = pb;
      pb = fmaf(ta, pb, tb);
      pa *= ta;
    }
  }
  __syncthreads();
  float h = sb[n * 17 + seg];
#pragma unroll 8
  for (int j = 0; j < 32; j++) {
    int g = seg * 32 + j;
    size_t off = ((size_t)(b * GCH + g) * DIN + d) * 16 + n;
    h0[off] = h;
    h = fmaf(ca[j], h, cb[j]);
  }
}

// ---------------- scan phase C: replay + gate, dt fused ----------------
__global__ __launch_bounds__(192, 3) void k_scanC(const unsigned short* __restrict__ uR,
    const float* __restrict__ xdbl, const float* __restrict__ Wdt,
    const float* __restrict__ bdt, const unsigned short* __restrict__ zR,
    const float* __restrict__ Alog, const float* __restrict__ Dp,
    const float* __restrict__ h0, unsigned short* __restrict__ yR) {
  int b = blockIdx.y, g = blockIdx.x, d = threadIdx.x;
  __shared__ float Bs[TCH * 16], Cs[TCH * 16], Dts[TCH * 8];
  for (int i = d; i < TCH * 16; i += 192) {
    int t = i >> 4, n = i & 15;
    size_t rb = (size_t)(b * LSEQ + g * TCH + t) * 38;
    Bs[i] = xdbl[rb + 6 + n];
    Cs[i] = xdbl[rb + 22 + n];
  }
  for (int i = d; i < TCH * 6; i += 192) {
    int t = i / 6, c = i - t * 6;
    Dts[t * 8 + c] = xdbl[(size_t)(b * LSEQ + g * TCH + t) * 38 + c];
  }
  float ac2[16];
#pragma unroll
  for (int n = 0; n < 16; n++) ac2[n] = -__expf(Alog[d * 16 + n]) * 1.44269504f;
  float wdt[6];
#pragma unroll
  for (int c = 0; c < 6; c++) wdt[c] = Wdt[d * 6 + c];
  float bd = bdt[d];
  float Dd = Dp[d];
  size_t base0 = (size_t)(b * LSEQ + g * TCH);
  float uu[TCH];
#pragma unroll
  for (int t = 0; t < TCH; t++) uu[t] = bf2f(uR[(base0 + t) * DIN + d]);
  size_t co = ((size_t)(b * GCH + g) * DIN + d) * 16;
  float h[16];
#pragma unroll
  for (int qq = 0; qq < 4; qq++) {
    float4 v = ((const float4*)(h0 + co))[qq];
    h[qq * 4] = v.x; h[qq * 4 + 1] = v.y; h[qq * 4 + 2] = v.z; h[qq * 4 + 3] = v.w;
  }
  __syncthreads();
  float dtv[TCH];
#pragma unroll
  for (int t = 0; t < TCH; t++) {
    float dr = bd;
#pragma unroll
    for (int c = 0; c < 6; c++) dr = fmaf(Dts[t * 8 + c], wdt[c], dr);
    dtv[t] = dr > 20.f ? dr : __logf(1.f + __expf(dr));
  }
#pragma unroll
  for (int t = 0; t < TCH; t++) {
    float du = dtv[t] * uu[t];
    float zv = bf2f(zR[(base0 + t) * DIN + d]);
    float bs[16], cs[16];
    const float4* sbp = (const float4*)&Bs[t * 16];
    const float4* scp = (const float4*)&Cs[t * 16];
#pragma unroll
    for (int qq = 0; qq < 4; qq++) {
      float4 vb = sbp[qq], vc = scp[qq];
      bs[qq * 4] = vb.x; bs[qq * 4 + 1] = vb.y; bs[qq * 4 + 2] = vb.z; bs[qq * 4 + 3] = vb.w;
      cs[qq * 4] = vc.x; cs[qq * 4 + 1] = vc.y; cs[qq * 4 + 2] = vc.z; cs[qq * 4 + 3] = vc.w;
    }
    float y0 = 0.f, y1 = 0.f, y2 = 0.f, y3 = 0.f;
#pragma unroll
    for (int n = 0; n < 16; n++) {
      float e = fexp2(dtv[t] * ac2[n]);
      h[n] = fmaf(h[n], e, du * bs[n]);
      float p = h[n] * cs[n];
      if ((n & 3) == 0) y0 += p; else if ((n & 3) == 1) y1 += p;
      else if ((n & 3) == 2) y2 += p; else y3 += p;
    }
    float yv = ((y0 + y1) + (y2 + y3)) + uu[t] * Dd;
    yR[(base0 + t) * DIN + d] = f2bf(yv * siluf(zv));
  }
}

// ---------------- launch ----------------
extern "C" void kernel_launch(void* const* d_in, const int* in_sizes, int n_in,
                              void* d_out, int out_size, void* d_ws, size_t ws_size,
                              hipStream_t stream) {
  (void)in_sizes; (void)n_in; (void)out_size; (void)ws_size;
  const float* x    = (const float*)d_in[0];
  const float* Hx   = (const float*)d_in[1];
  const float* c1w  = (const float*)d_in[2];
  const float* c1b  = (const float*)d_in[3];
  const float* c2w  = (const float*)d_in[4];
  const float* c2b  = (const float*)d_in[5];
  const float* c3w  = (const float*)d_in[6];
  const float* c3b  = (const float*)d_in[7];
  const float* Win  = (const float*)d_in[8];
  const float* w1d  = (const float*)d_in[9];
  const float* b1d  = (const float*)d_in[10];
  const float* Wx   = (const float*)d_in[11];
  const float* Wdt  = (const float*)d_in[12];
  const float* bdt  = (const float*)d_in[13];
  const float* Alog = (const float*)d_in[14];
  const float* Dp   = (const float*)d_in[15];
  const float* Wout = (const float*)d_in[16];
  float* out = (float*)d_out;

  float* ws = (float*)d_ws;
  const size_t F = (size_t)2 * 96 * LSEQ;   // 3,145,728 floats
  const size_t Fh = F / 2;

  // R10 layout (floats), total 7F + 92,544 ~= 88 MB:
  //  [0,F)      h3 (conv3-1x1 -> normselu2) -> chA (scanA -> scanB)
  //  [F,2F)     Lx f32 planar (normselu2 -> outproj)
  //  [2F,2.5F)  R1: h1 rows96 (conv1 -> conv3x3) -> LxR rows96 (normselu2 -> inproj)
  //  [2.5F,3F)  R2: h2 rows96 (conv3x3 -> conv3-1x1) -> xdbl f32 rows38 (xproj -> scans)
  //  [3F,4.5F)  UH bf16 rows288 (upcat -> conv1); then xzx f32 rows192 [3F,5F)
  //             (inproj -> conv1d); then chB [3F,4F) (scanA -> scanB) -> yR [3F,4F)
  //             (scanC -> outproj)
  //  [4F,5F)    h0 (scanB -> scanC)   [xzx dead after conv1d]
  //  [5F,6F)    zR bf16 rows192 (inproj -> scanC)
  //  [6F,7F)    R3: uR bf16 rows192 (conv1d -> xproj, scanA, scanC)
  //  [7F,...]   Wp (92160) + stats (384)
  float*          b_h3 = ws;
  float*          chA  = ws;
  float*          b_Lx = ws + F;
  unsigned short* R1   = (unsigned short*)(ws + 2 * F);
  unsigned short* R2   = (unsigned short*)(ws + 2 * F + Fh);
  float*          xdbl = ws + 2 * F + Fh;
  unsigned short* UH   = (unsigned short*)(ws + 3 * F);
  float*          xzx  = ws + 3 * F;
  float*          chB  = ws + 3 * F;
  unsigned short* yRb  = (unsigned short*)(ws + 3 * F);
  float*          h0b  = ws + 4 * F;
  unsigned short* zRb  = (unsigned short*)(ws + 5 * F);
  unsigned short* R3   = (unsigned short*)(ws + 6 * F);
  unsigned short* Wp   = (unsigned short*)(ws + 7 * F);
  float*          b_st = ws + 7 * F + 92160;

  k_packw<<<dim3(720), dim3(256), 0, stream>>>(c1w, c2w, c3w, Win, Wx, Wout, Wp);
  k_upcat<<<dim3(256, 2), dim3(256), 0, stream>>>(x, Hx, UH);
  k_gemm<OUT_BF16R, 6><<<dim3(256, 1), dim3(256), 0, stream>>>(
      UH, Wp, c1b, R1, nullptr, nullptr, 288, 0, 0);
  k_conv3x3m<<<dim3(512), dim3(256), 0, stream>>>(R1, Wp + 27648, c2b, R2);
  k_gemm<OUT_F32P, 6><<<dim3(256, 1), dim3(256), 0, stream>>>(
      R2, Wp + 110592, c3b, b_h3, nullptr, nullptr, 96, 0, 0);
  k_stats<<<dim3(192), dim3(256), 0, stream>>>(b_h3, b_st);
  k_normselu2<<<dim3(256, 2), dim3(256), 0, stream>>>(b_h3, b_st, b_Lx, R1);
  k_gemm<OUT_XZ, 6><<<dim3(256, 4), dim3(256), 0, stream>>>(
      R1, Wp + 119808, nullptr, xzx, zRb, nullptr, 96, 192, 0);
  k_conv1d<<<dim3((2 * LSEQ * DIN + 255) / 256), dim3(256), 0, stream>>>(xzx, w1d, b1d, R3);
  k_gemm<OUT_F32R, 3><<<dim3(256, 1), dim3(256), 0, stream>>>(
      R3, Wp + 156672, nullptr, xdbl, nullptr, nullptr, 192, 38, 38);
  k_scanA<<<dim3(GCH, 2), dim3(192), 0, stream>>>(R3, xdbl, Wdt, bdt, Alog, chA, chB);
  k_scanB<<<dim3(2 * DIN), dim3(256), 0, stream>>>(chA, chB, h0b);
  k_scanC<<<dim3(GCH, 2), dim3(192), 0, stream>>>(R3, xdbl, Wdt, bdt, zRb, Alog, Dp, h0b, yRb);
  k_gemm<OUT_F32P_RES, 6><<<dim3(256, 1), dim3(256), 0, stream>>>(
      yRb, Wp + 165888, nullptr, out, nullptr, b_Lx, 192, 0, 0);
}